// Round 2
// baseline (324.323 us; speedup 1.0000x reference)
//
#include <hip/hip_runtime.h>
#include <math.h>

// Problem constants
#define BATCH 2
#define SEQ   1024
#define DMODEL 512
#define NHEAD 8
#define HDIM  64
#define FFND  2048
#define BH    (BATCH*NHEAD)   // 16

typedef float  f32x4  __attribute__((ext_vector_type(4)));
typedef __bf16 bf16x8 __attribute__((ext_vector_type(8)));

__device__ __forceinline__ unsigned short f2bf(float f) {
  union { float f; unsigned u; } x; x.f = f;
  unsigned r = x.u + 0x7fffu + ((x.u >> 16) & 1u);
  return (unsigned short)(r >> 16);
}
__device__ __forceinline__ float bf2f(unsigned short h) {
  union { unsigned u; float f; } x; x.u = ((unsigned)h) << 16;
  return x.f;
}

__device__ __forceinline__ void load_lds16(const void* g, void* l) {
  __builtin_amdgcn_global_load_lds((const __attribute__((address_space(1))) void*)g,
                                   (__attribute__((address_space(3))) void*)l, 16, 0, 0);
}

// ---------------------------------------------------------------- prep ----
__global__ __launch_bounds__(256) void prep_misc(
    const float* __restrict__ x, const float* __restrict__ bq,
    const float* __restrict__ bk, const float* __restrict__ bv,
    unsigned short* __restrict__ xb, float* __restrict__ bqkv) {
  int gid = blockIdx.x * 256 + threadIdx.x;       // grid 4096 -> 1,048,576
  xb[gid] = f2bf(x[gid]);
  if (gid < 1536)
    bqkv[gid] = gid < 512 ? bq[gid] : (gid < 1024 ? bk[gid - 512] : bv[gid - 1024]);
}

// transpose+cast: src f32 [R][C] -> dst bf16 [C][R]; grid (C/32, R/32), block (32,8)
__global__ __launch_bounds__(256) void tcast(
    const float* __restrict__ src, unsigned short* __restrict__ dst, int R, int C) {
  __shared__ float t[32][33];
  int c0 = blockIdx.x * 32, r0 = blockIdx.y * 32;
  int tx = threadIdx.x, ty = threadIdx.y;
#pragma unroll
  for (int i = 0; i < 4; i++)
    t[ty + i * 8][tx] = src[(size_t)(r0 + ty + i * 8) * C + c0 + tx];
  __syncthreads();
#pragma unroll
  for (int i = 0; i < 4; i++)
    dst[(size_t)(c0 + ty + i * 8) * R + r0 + tx] = f2bf(t[tx][ty + i * 8]);
}

// ---------------------------------------------------------------- RPE -----
// rpe[b][h][i][j] = (relu(rel_pos[b,i,j,:]@R1 + rb1)@R2 + rb2)[h], stored bf16
#define RPAIRS 4
__global__ __launch_bounds__(256) void rpe_kernel(
    const float* __restrict__ rel, const float* __restrict__ R1,
    const float* __restrict__ rb1, const float* __restrict__ R2,
    const float* __restrict__ rb2, unsigned short* __restrict__ rpe) {
  __shared__ float R1s[256], rb1s[64], R2s[512], rb2s[8];
  int tid = threadIdx.x;
  R1s[tid] = R1[tid & 255];
  if (tid < 64) rb1s[tid] = rb1[tid];
  for (int i = tid; i < 512; i += 256) R2s[i] = R2[i];
  if (tid < 8) rb2s[tid] = rb2[tid];
  __syncthreads();

  const int stride = gridDim.x * 256;             // 524288
  float4 rp[RPAIRS];
  int pidx[RPAIRS];
#pragma unroll
  for (int u = 0; u < RPAIRS; u++) {
    int p = blockIdx.x * 256 + tid + u * stride;
    pidx[u] = p;
    rp[u] = ((const float4*)rel)[p];
  }
  float o[RPAIRS][8];
#pragma unroll
  for (int u = 0; u < RPAIRS; u++)
#pragma unroll
    for (int h = 0; h < 8; h++) o[u][h] = rb2s[h];

  for (int t = 0; t < 64; t++) {
    float r0 = R1s[t], r1 = R1s[64 + t], r2 = R1s[128 + t], r3 = R1s[192 + t];
    float bb = rb1s[t];
    float4 ra = ((const float4*)R2s)[t * 2];
    float4 rbv = ((const float4*)R2s)[t * 2 + 1];
#pragma unroll
    for (int u = 0; u < RPAIRS; u++) {
      float hv = bb + rp[u].x * r0 + rp[u].y * r1 + rp[u].z * r2 + rp[u].w * r3;
      hv = fmaxf(hv, 0.f);
      o[u][0] += hv * ra.x;  o[u][1] += hv * ra.y;
      o[u][2] += hv * ra.z;  o[u][3] += hv * ra.w;
      o[u][4] += hv * rbv.x; o[u][5] += hv * rbv.y;
      o[u][6] += hv * rbv.z; o[u][7] += hv * rbv.w;
    }
  }
#pragma unroll
  for (int u = 0; u < RPAIRS; u++) {
    int p = pidx[u];
    int b = p >> 20, ij = p & 1048575;
    size_t base = ((size_t)b * 8) << 20;
#pragma unroll
    for (int h = 0; h < 8; h++)
      rpe[base + ((size_t)h << 20) + ij] = f2bf(o[u][h]);
  }
}

// ---------------------------------------------------------------- GEMM ----
// C[M][N] = A[M][K] (bf16 rm) * Bt[N][K] (bf16, pre-transposed) + bias
enum { EPI_F32 = 0, EPI_GELU = 1, EPI_QKV = 2 };
#define BM 128
#define BN 128
#define BKK 64

template <int EPI>
__global__ __launch_bounds__(256, 2) void gemm_bt(
    const unsigned short* __restrict__ A, const unsigned short* __restrict__ Bt,
    const float* __restrict__ bias, void* __restrict__ O0, void* __restrict__ O1,
    void* __restrict__ O2, int M, int N, int K) {
  __shared__ unsigned short As[BM * BKK];
  __shared__ unsigned short Bs[BN * BKK];
  const int tid = threadIdx.x, lane = tid & 63, w = tid >> 6;
  const int wr = w >> 1, wc = w & 1;
  const int m0 = blockIdx.y * BM, n0 = blockIdx.x * BN;
  const int l15 = lane & 15, l4g = lane >> 4;

  f32x4 acc[4][4];
#pragma unroll
  for (int i = 0; i < 4; i++)
#pragma unroll
    for (int j = 0; j < 4; j++) acc[i][j] = (f32x4){0.f, 0.f, 0.f, 0.f};

  const int nkt = K / BKK;
  for (int kt = 0; kt < nkt; ++kt) {
#pragma unroll
    for (int it = 0; it < 4; ++it) {
      int c = it * 256 + tid;
      int row = c >> 3, c8 = (c & 7) * 8;
      load_lds16(A + (size_t)(m0 + row) * K + kt * BKK + c8, (char*)As + c * 16);
    }
#pragma unroll
    for (int it = 0; it < 4; ++it) {
      int c = it * 256 + tid;
      int row = c >> 3, c8 = (c & 7) * 8;
      load_lds16(Bt + (size_t)(n0 + row) * K + kt * BKK + c8, (char*)Bs + c * 16);
    }
    asm volatile("s_waitcnt vmcnt(0)" ::: "memory");
    __syncthreads();
#pragma unroll
    for (int kk = 0; kk < 2; ++kk) {
      bf16x8 af[4], bfv[4];
#pragma unroll
      for (int i = 0; i < 4; i++)
        af[i] = *(const bf16x8*)&As[(wr * 64 + i * 16 + l15) * BKK + kk * 32 + l4g * 8];
#pragma unroll
      for (int j = 0; j < 4; j++)
        bfv[j] = *(const bf16x8*)&Bs[(wc * 64 + j * 16 + l15) * BKK + kk * 32 + l4g * 8];
#pragma unroll
      for (int i = 0; i < 4; i++)
#pragma unroll
        for (int j = 0; j < 4; j++)
          acc[i][j] = __builtin_amdgcn_mfma_f32_16x16x32_bf16(af[i], bfv[j], acc[i][j], 0, 0, 0);
    }
    __syncthreads();
  }

#pragma unroll
  for (int i = 0; i < 4; i++) {
    int row = m0 + wr * 64 + i * 16 + l4g * 4;
#pragma unroll
    for (int j = 0; j < 4; j++) {
      int col = n0 + wc * 64 + j * 16 + l15;
      float bv = bias ? bias[col] : 0.f;
#pragma unroll
      for (int r = 0; r < 4; r++) {
        float v = acc[i][j][r] + bv;
        int rr = row + r;
        if (EPI == EPI_F32) {
          ((float*)O0)[(size_t)rr * N + col] = v;
        } else if (EPI == EPI_GELU) {
          float gv = 0.5f * v * (1.f + erff(v * 0.70710678118f));
          ((unsigned short*)O0)[(size_t)rr * N + col] = f2bf(gv);
        } else {  // QKV scatter
          int b = rr >> 10, n = rr & 1023;
          int d = col & 511, h = d >> 6, hd = d & 63;
          int bh = b * 8 + h;
          unsigned short bv16 = f2bf(v);
          if (col < 512)
            ((unsigned short*)O0)[((size_t)bh * 1024 + n) * 64 + hd] = bv16;
          else if (col < 1024)
            ((unsigned short*)O1)[((size_t)bh * 1024 + n) * 64 + hd] = bv16;
          else
            ((unsigned short*)O2)[((size_t)bh * 64 + hd) * 1024 + n] = bv16;
        }
      }
    }
  }
}

// ------------------------------------------------------------- attention --
// grid 256: block = (bh, 64-query tile). 4 waves x 16 rows. online softmax.
__global__ __launch_bounds__(256, 2) void attn_kernel(
    const unsigned short* __restrict__ Qh, const unsigned short* __restrict__ Kh,
    const unsigned short* __restrict__ VT, const unsigned short* __restrict__ rpe,
    unsigned short* __restrict__ AO) {
  __shared__ unsigned short Ks[64 * 64], Vs[64 * 64], Rs[64 * 64];
  __shared__ unsigned short Ps[4][16 * 64];
  const int tid = threadIdx.x, lane = tid & 63, w = tid >> 6;
  const int l15 = lane & 15, l4g = lane >> 4;
  const int bh = blockIdx.x >> 4, it = blockIdx.x & 15;
  const int i0 = it * 64;
  const unsigned short* Qb = Qh + (size_t)bh * SEQ * HDIM;
  const unsigned short* Kb = Kh + (size_t)bh * SEQ * HDIM;
  const unsigned short* Vb = VT + (size_t)bh * HDIM * SEQ;
  const unsigned short* Rb = rpe + ((size_t)bh << 20);

  bf16x8 qf[2];
#pragma unroll
  for (int kk = 0; kk < 2; kk++)
    qf[kk] = *(const bf16x8*)&Qb[(size_t)(i0 + w * 16 + l15) * 64 + kk * 32 + l4g * 8];

  f32x4 o[4];
#pragma unroll
  for (int i = 0; i < 4; i++) o[i] = (f32x4){0.f, 0.f, 0.f, 0.f};
  float m4[4], l4s[4];
#pragma unroll
  for (int r = 0; r < 4; r++) { m4[r] = -1e30f; l4s[r] = 0.f; }

  for (int jt = 0; jt < 16; ++jt) {
    int j0 = jt * 64;
#pragma unroll
    for (int itn = 0; itn < 2; ++itn) {
      int c = itn * 256 + tid, row = c >> 3, c8 = (c & 7) * 8;
      load_lds16(Kb + (size_t)(j0 + row) * 64 + c8, (char*)Ks + c * 16);
    }
#pragma unroll
    for (int itn = 0; itn < 2; ++itn) {
      int c = itn * 256 + tid, row = c >> 3, c8 = (c & 7) * 8;
      load_lds16(Vb + (size_t)row * SEQ + j0 + c8, (char*)Vs + c * 16);
    }
#pragma unroll
    for (int itn = 0; itn < 2; ++itn) {
      int c = itn * 256 + tid, row = c >> 3, c8 = (c & 7) * 8;
      load_lds16(Rb + (size_t)(i0 + row) * SEQ + j0 + c8, (char*)Rs + c * 16);
    }
    asm volatile("s_waitcnt vmcnt(0)" ::: "memory");
    __syncthreads();

    f32x4 sa[4];
#pragma unroll
    for (int js = 0; js < 4; js++) sa[js] = (f32x4){0.f, 0.f, 0.f, 0.f};
#pragma unroll
    for (int kk = 0; kk < 2; kk++) {
#pragma unroll
      for (int js = 0; js < 4; js++) {
        bf16x8 kb = *(const bf16x8*)&Ks[(js * 16 + l15) * 64 + kk * 32 + l4g * 8];
        sa[js] = __builtin_amdgcn_mfma_f32_16x16x32_bf16(qf[kk], kb, sa[js], 0, 0, 0);
      }
    }
    // scores + rpe, row max
    float p[4][4], mx[4];
#pragma unroll
    for (int r = 0; r < 4; r++) mx[r] = -1e30f;
#pragma unroll
    for (int js = 0; js < 4; js++)
#pragma unroll
      for (int r = 0; r < 4; r++) {
        float rv = bf2f(Rs[(w * 16 + l4g * 4 + r) * 64 + js * 16 + l15]);
        float s = sa[js][r] * 0.125f + rv;
        p[js][r] = s;
        mx[r] = fmaxf(mx[r], s);
      }
#pragma unroll
    for (int off = 1; off < 16; off <<= 1)
#pragma unroll
      for (int r = 0; r < 4; r++) mx[r] = fmaxf(mx[r], __shfl_xor(mx[r], off));
    float al[4], sm[4];
#pragma unroll
    for (int r = 0; r < 4; r++) {
      float nm = fmaxf(m4[r], mx[r]);
      al[r] = __expf(m4[r] - nm);
      m4[r] = nm;
      sm[r] = 0.f;
    }
#pragma unroll
    for (int js = 0; js < 4; js++)
#pragma unroll
      for (int r = 0; r < 4; r++) {
        float e = __expf(p[js][r] - m4[r]);
        p[js][r] = e;
        sm[r] += e;
      }
#pragma unroll
    for (int off = 1; off < 16; off <<= 1)
#pragma unroll
      for (int r = 0; r < 4; r++) sm[r] += __shfl_xor(sm[r], off);
#pragma unroll
    for (int r = 0; r < 4; r++) l4s[r] = l4s[r] * al[r] + sm[r];
#pragma unroll
    for (int hdf = 0; hdf < 4; hdf++)
#pragma unroll
      for (int r = 0; r < 4; r++) o[hdf][r] *= al[r];
    // P -> LDS (wave-private) for A-fragment layout
#pragma unroll
    for (int js = 0; js < 4; js++)
#pragma unroll
      for (int r = 0; r < 4; r++)
        Ps[w][(l4g * 4 + r) * 64 + js * 16 + l15] = f2bf(p[js][r]);
    // PV
#pragma unroll
    for (int kk = 0; kk < 2; kk++) {
      bf16x8 pf = *(const bf16x8*)&Ps[w][l15 * 64 + kk * 32 + l4g * 8];
#pragma unroll
      for (int hdf = 0; hdf < 4; hdf++) {
        bf16x8 vb = *(const bf16x8*)&Vs[(hdf * 16 + l15) * 64 + kk * 32 + l4g * 8];
        o[hdf] = __builtin_amdgcn_mfma_f32_16x16x32_bf16(pf, vb, o[hdf], 0, 0, 0);
      }
    }
    __syncthreads();
  }
  const int b = bh >> 3, h = bh & 7;
#pragma unroll
  for (int hdf = 0; hdf < 4; hdf++)
#pragma unroll
    for (int r = 0; r < 4; r++) {
      float v = o[hdf][r] / l4s[r];
      int n = i0 + w * 16 + l4g * 4 + r;
      AO[((size_t)b * SEQ + n) * DMODEL + h * 64 + hdf * 16 + l15] = f2bf(v);
    }
}

// ---------------------------------------------------------------- LN ------
__global__ __launch_bounds__(256) void ln_kernel(
    const float* __restrict__ a, const float* __restrict__ res,
    const float* __restrict__ g, const float* __restrict__ be,
    float* __restrict__ outf, unsigned short* __restrict__ outb) {
  const int row = blockIdx.x, t = threadIdx.x;
  const float* pa = a + (size_t)row * DMODEL;
  const float* pb = res + (size_t)row * DMODEL;
  float v0 = pa[t] + pb[t];
  float v1 = pa[t + 256] + pb[t + 256];
  float s = v0 + v1, sq = v0 * v0 + v1 * v1;
#pragma unroll
  for (int off = 1; off < 64; off <<= 1) {
    s += __shfl_xor(s, off);
    sq += __shfl_xor(sq, off);
  }
  __shared__ float ls[4], lq[4];
  int w = t >> 6, lane = t & 63;
  if (lane == 0) { ls[w] = s; lq[w] = sq; }
  __syncthreads();
  s = ls[0] + ls[1] + ls[2] + ls[3];
  sq = lq[0] + lq[1] + lq[2] + lq[3];
  float mu = s * (1.f / DMODEL);
  float var = sq * (1.f / DMODEL) - mu * mu;
  float rs = rsqrtf(var + 1e-5f);
  float y0 = (v0 - mu) * rs * g[t] + be[t];
  float y1v = (v1 - mu) * rs * g[t + 256] + be[t + 256];
  outf[(size_t)row * DMODEL + t] = y0;
  outf[(size_t)row * DMODEL + t + 256] = y1v;
  if (outb) {
    outb[(size_t)row * DMODEL + t] = f2bf(y0);
    outb[(size_t)row * DMODEL + t + 256] = f2bf(y1v);
  }
}

// ---------------------------------------------------------------- launch --
extern "C" void kernel_launch(void* const* d_in, const int* in_sizes, int n_in,
                              void* d_out, int out_size, void* d_ws, size_t ws_size,
                              hipStream_t stream) {
  const float* x   = (const float*)d_in[0];
  const float* rel = (const float*)d_in[1];
  const float* Wq  = (const float*)d_in[2];
  const float* bq  = (const float*)d_in[3];
  const float* Wk  = (const float*)d_in[4];
  const float* bk  = (const float*)d_in[5];
  const float* Wv  = (const float*)d_in[6];
  const float* bv  = (const float*)d_in[7];
  const float* Wo  = (const float*)d_in[8];
  const float* bo  = (const float*)d_in[9];
  const float* R1  = (const float*)d_in[10];
  const float* rb1 = (const float*)d_in[11];
  const float* R2  = (const float*)d_in[12];
  const float* rb2 = (const float*)d_in[13];
  const float* g1  = (const float*)d_in[14];
  const float* b1  = (const float*)d_in[15];
  const float* g2  = (const float*)d_in[16];
  const float* b2  = (const float*)d_in[17];
  const float* F1  = (const float*)d_in[18];
  const float* fb1 = (const float*)d_in[19];
  const float* F2  = (const float*)d_in[20];
  const float* fb2 = (const float*)d_in[21];

  char* p = (char*)d_ws;
  auto alloc = [&](size_t bytes) {
    char* r = p;
    p += (bytes + 255) & ~(size_t)255;
    return r;
  };
  unsigned short* xb   = (unsigned short*)alloc((size_t)2048 * 512 * 2);
  unsigned short* qkvT = (unsigned short*)alloc((size_t)1536 * 512 * 2);
  float*          bqkv = (float*)alloc(1536 * 4);
  unsigned short* WoT  = (unsigned short*)alloc((size_t)512 * 512 * 2);
  unsigned short* F1T  = (unsigned short*)alloc((size_t)2048 * 512 * 2);
  unsigned short* F2T  = (unsigned short*)alloc((size_t)512 * 2048 * 2);
  unsigned short* Qhp  = (unsigned short*)alloc((size_t)BH * SEQ * HDIM * 2);
  unsigned short* Khp  = (unsigned short*)alloc((size_t)BH * SEQ * HDIM * 2);
  unsigned short* VTp  = (unsigned short*)alloc((size_t)BH * HDIM * SEQ * 2);
  unsigned short* rpep = (unsigned short*)alloc((size_t)BH * SEQ * SEQ * 2);   // 32MB
  unsigned short* attO = (unsigned short*)alloc((size_t)2048 * 512 * 2);
  float*          t1   = (float*)alloc((size_t)2048 * 512 * 4);
  float*          y1   = (float*)alloc((size_t)2048 * 512 * 4);
  unsigned short* y1b  = (unsigned short*)alloc((size_t)2048 * 512 * 2);
  float*          t2   = t1;                     // t1 dead after LN1
  unsigned short* hbuf = rpep;                   // rpe dead after attention (8MB < 32MB)

  // prep
  prep_misc<<<4096, 256, 0, stream>>>(x, bq, bk, bv, xb, bqkv);
  dim3 tb(32, 8);
  tcast<<<dim3(16, 16), tb, 0, stream>>>(Wq, qkvT, 512, 512);
  tcast<<<dim3(16, 16), tb, 0, stream>>>(Wk, qkvT + 512 * 512, 512, 512);
  tcast<<<dim3(16, 16), tb, 0, stream>>>(Wv, qkvT + 1024 * 512, 512, 512);
  tcast<<<dim3(16, 16), tb, 0, stream>>>(Wo, WoT, 512, 512);
  tcast<<<dim3(64, 16), tb, 0, stream>>>(F1, F1T, 512, 2048);
  tcast<<<dim3(16, 64), tb, 0, stream>>>(F2, F2T, 2048, 512);

  // rpe scores
  rpe_kernel<<<2048, 256, 0, stream>>>(rel, R1, rb1, R2, rb2, rpep);

  // QKV projection
  gemm_bt<EPI_QKV><<<dim3(12, 16), 256, 0, stream>>>(xb, qkvT, bqkv, Qhp, Khp, VTp,
                                                     2048, 1536, 512);
  // attention
  attn_kernel<<<256, 256, 0, stream>>>(Qhp, Khp, VTp, rpep, attO);

  // out projection
  gemm_bt<EPI_F32><<<dim3(4, 16), 256, 0, stream>>>(attO, WoT, bo, t1, nullptr, nullptr,
                                                    2048, 512, 512);
  // LN1 (residual x + t1) -> y1 (f32) + y1b (bf16)
  ln_kernel<<<2048, 256, 0, stream>>>(x, t1, g1, b1, y1, y1b);

  // FFN
  gemm_bt<EPI_GELU><<<dim3(16, 16), 256, 0, stream>>>(y1b, F1T, fb1, hbuf, nullptr, nullptr,
                                                      2048, 2048, 512);
  gemm_bt<EPI_F32><<<dim3(4, 16), 256, 0, stream>>>(hbuf, F2T, fb2, t2, nullptr, nullptr,
                                                    2048, 512, 2048);
  // LN2 -> out
  ln_kernel<<<2048, 256, 0, stream>>>(y1, t2, g2, b2, (float*)d_out, nullptr);
}

// Round 3
// 312.085 us; speedup vs baseline: 1.0392x; 1.0392x over previous
//
#include <hip/hip_runtime.h>
#include <math.h>

// Problem constants
#define BATCH 2
#define SEQ   1024
#define DMODEL 512
#define NHEAD 8
#define HDIM  64
#define FFND  2048
#define BH    (BATCH*NHEAD)   // 16

typedef float  f32x4  __attribute__((ext_vector_type(4)));
typedef __bf16 bf16x8 __attribute__((ext_vector_type(8)));

__device__ __forceinline__ unsigned short f2bf(float f) {
  union { float f; unsigned u; } x; x.f = f;
  unsigned r = x.u + 0x7fffu + ((x.u >> 16) & 1u);
  return (unsigned short)(r >> 16);
}
__device__ __forceinline__ float bf2f(unsigned short h) {
  union { unsigned u; float f; } x; x.u = ((unsigned)h) << 16;
  return x.f;
}
__device__ __forceinline__ unsigned pk2(float a, float b) {
  return (unsigned)f2bf(a) | ((unsigned)f2bf(b) << 16);
}

__device__ __forceinline__ void load_lds16(const void* g, void* l) {
  __builtin_amdgcn_global_load_lds((const __attribute__((address_space(1))) void*)g,
                                   (__attribute__((address_space(3))) void*)l, 16, 0, 0);
}

// ---------------------------------------------------------------- prep ----
// x -> bf16 (float4 vectorized) + pack qkv bias. grid 1024 x 256.
__global__ __launch_bounds__(256) void prep_misc(
    const float* __restrict__ x, const float* __restrict__ bq,
    const float* __restrict__ bk, const float* __restrict__ bv,
    unsigned short* __restrict__ xb, float* __restrict__ bqkv) {
  int gid = blockIdx.x * 256 + threadIdx.x;       // 262144 threads x 4 els
  float4 v = ((const float4*)x)[gid];
  ushort4 s;
  s.x = f2bf(v.x); s.y = f2bf(v.y); s.z = f2bf(v.z); s.w = f2bf(v.w);
  ((ushort4*)xb)[gid] = s;
  if (gid < 1536)
    bqkv[gid] = gid < 512 ? bq[gid] : (gid < 1024 ? bk[gid - 512] : bv[gid - 1024]);
}

// all weight transposes fused: src f32 [R][C] -> dst bf16 [C][R]. block (32,8).
__global__ __launch_bounds__(256) void prep_weights(
    const float* __restrict__ Wq, const float* __restrict__ Wk,
    const float* __restrict__ Wv, const float* __restrict__ Wo,
    const float* __restrict__ F1, const float* __restrict__ F2,
    unsigned short* __restrict__ qkvT, unsigned short* __restrict__ WoT,
    unsigned short* __restrict__ F1T, unsigned short* __restrict__ F2T) {
  __shared__ float t[32][33];
  int bid = blockIdx.x;
  const float* src; unsigned short* dst; int R, C, tx, ty;
  if (bid < 1024) {
    int m = bid >> 8;
    src = m == 0 ? Wq : m == 1 ? Wk : m == 2 ? Wv : Wo;
    dst = m < 3 ? qkvT + m * 512 * 512 : WoT;
    R = 512; C = 512; int u = bid & 255; tx = u & 15; ty = u >> 4;
  } else if (bid < 2048) {
    src = F1; dst = F1T; R = 512; C = 2048;
    int u = bid - 1024; tx = u & 63; ty = u >> 6;
  } else {
    src = F2; dst = F2T; R = 2048; C = 512;
    int u = bid - 2048; tx = u & 15; ty = u >> 4;
  }
  int c0 = tx * 32, r0 = ty * 32;
  int x_ = threadIdx.x, y_ = threadIdx.y;
#pragma unroll
  for (int i = 0; i < 4; i++)
    t[y_ + i * 8][x_] = src[(size_t)(r0 + y_ + i * 8) * C + c0 + x_];
  __syncthreads();
#pragma unroll
  for (int i = 0; i < 4; i++)
    dst[(size_t)(c0 + y_ + i * 8) * R + r0 + x_] = f2bf(t[x_][y_ + i * 8]);
}

// ---------------------------------------------------------------- RPE -----
// rpe[b][h][i][j] = (relu(rel[b,i,j,:]@R1 + rb1)@R2 + rb2)[h], bf16 out.
// MFMA version: per wave, 64 pair-rows per iteration.
// GEMM1': hidden^T[dim][row] = R1^T @ rel^T  (K=4 zero-padded to 32)
// LDS transpose (wave-private, XOR-swizzled), then
// GEMM2: out[row][h] = hidden @ R2          (N=8 zero-padded to 16)
__global__ __launch_bounds__(256) void rpe_mfma(
    const float* __restrict__ rel, const float* __restrict__ R1,
    const float* __restrict__ rb1, const float* __restrict__ R2,
    const float* __restrict__ rb2, unsigned short* __restrict__ rpe) {
  __shared__ unsigned short Hs[4][64 * 64];   // 8KB per wave
  __shared__ unsigned short Os[4][8 * 64];    // 1KB per wave
  const int tid = threadIdx.x, lane = tid & 63, w = tid >> 6;
  const int l15 = lane & 15, l4g = lane >> 4;
  char* Hw = (char*)&Hs[w][0];
  char* Ow = (char*)&Os[w][0];

  // --- preload constant fragments ---
  // GEMM1 A-frag[mt]: lane holds R1[k=j][m=mt*16+l15] for l4g==0, j<4, else 0
  bf16x8 a1[4];
#pragma unroll
  for (int mt = 0; mt < 4; mt++) {
    bf16x8 z = {};
    if (l4g == 0) {
      int m = mt * 16 + l15;
      z[0] = (__bf16)R1[0 * 64 + m];
      z[1] = (__bf16)R1[1 * 64 + m];
      z[2] = (__bf16)R1[2 * 64 + m];
      z[3] = (__bf16)R1[3 * 64 + m];
    }
    a1[mt] = z;
  }
  // hidden bias per-lane: rb1v[mt][r] = rb1[mt*16 + l4g*4 + r]
  float rb1v[4][4];
#pragma unroll
  for (int mt = 0; mt < 4; mt++)
#pragma unroll
    for (int r = 0; r < 4; r++) rb1v[mt][r] = rb1[mt * 16 + l4g * 4 + r];
  // GEMM2 B-frag[ks]: lane holds R2[k=ks*32+l4g*8+j][n=l15] for l15<8, else 0
  bf16x8 b2f[2];
#pragma unroll
  for (int ks = 0; ks < 2; ks++) {
    bf16x8 z = {};
    if (l15 < 8) {
#pragma unroll
      for (int j = 0; j < 8; j++)
        z[j] = (__bf16)R2[(ks * 32 + l4g * 8 + j) * 8 + l15];
    }
    b2f[ks] = z;
  }
  float rb2v = (l15 < 8) ? rb2[l15] : 0.f;

  const int nwaves = gridDim.x * 4;            // 4096
  const int wgid = blockIdx.x * 4 + w;
  for (int itr = 0; itr < 8; itr++) {
    int p0 = (wgid + itr * nwaves) * 64;       // 64-row block base (pair idx)
    // B-frags: lanes l4g==0 load rel rows directly (256B coalesced per nt)
    bf16x8 b1[4];
#pragma unroll
    for (int nt = 0; nt < 4; nt++) {
      bf16x8 z = {};
      if (l4g == 0) {
        float4 rv = *(const float4*)&rel[(size_t)(p0 + nt * 16 + l15) * 4];
        z[0] = (__bf16)rv.x; z[1] = (__bf16)rv.y;
        z[2] = (__bf16)rv.z; z[3] = (__bf16)rv.w;
      }
      b1[nt] = z;
    }
    // GEMM1': hacc[mt][nt] = hidden^T tile (dim=mt, rows=nt)
#pragma unroll
    for (int nt = 0; nt < 4; nt++) {
#pragma unroll
      for (int mt = 0; mt < 4; mt++) {
        f32x4 hacc = __builtin_amdgcn_mfma_f32_16x16x32_bf16(
            a1[mt], b1[nt], (f32x4){0.f, 0.f, 0.f, 0.f}, 0, 0, 0);
        // lane: row = nt*16+l15, dims = mt*16 + l4g*4 + r
        int row = nt * 16 + l15;
        int dim0 = mt * 16 + l4g * 4;
        float v0 = fmaxf(hacc[0] + rb1v[mt][0], 0.f);
        float v1 = fmaxf(hacc[1] + rb1v[mt][1], 0.f);
        float v2 = fmaxf(hacc[2] + rb1v[mt][2], 0.f);
        float v3 = fmaxf(hacc[3] + rb1v[mt][3], 0.f);
        int byte = (row * 128 + dim0 * 2) ^ ((row & 7) << 4);
        uint2 pk; pk.x = pk2(v0, v1); pk.y = pk2(v2, v3);
        *(uint2*)(Hw + byte) = pk;                    // ds_write_b64
      }
    }
    // GEMM2: out[row][h]
    f32x4 acc2[4];
#pragma unroll
    for (int mt = 0; mt < 4; mt++) acc2[mt] = (f32x4){0.f, 0.f, 0.f, 0.f};
#pragma unroll
    for (int ks = 0; ks < 2; ks++) {
#pragma unroll
      for (int mt = 0; mt < 4; mt++) {
        int row = mt * 16 + l15;
        int byte = (row * 128 + (ks * 32 + l4g * 8) * 2) ^ ((l15 & 7) << 4);
        bf16x8 af = *(const bf16x8*)(Hw + byte);      // ds_read_b128
        acc2[mt] = __builtin_amdgcn_mfma_f32_16x16x32_bf16(af, b2f[ks], acc2[mt], 0, 0, 0);
      }
    }
    // out -> Os [h][row] swizzled (only h=l15<8 valid)
#pragma unroll
    for (int mt = 0; mt < 4; mt++) {
      if (l15 < 8) {
        int byte = (l15 * 128 + (mt * 16 + l4g * 4) * 2) ^ ((l15 & 7) << 4);
        uint2 pk;
        pk.x = pk2(acc2[mt][0] + rb2v, acc2[mt][1] + rb2v);
        pk.y = pk2(acc2[mt][2] + rb2v, acc2[mt][3] + rb2v);
        *(uint2*)(Ow + byte) = pk;                    // ds_write_b64
      }
    }
    // coalesced store: lane l -> h=l>>3, rows (l&7)*8..+7 (16B contiguous)
    {
      int h = lane >> 3, rb = (lane & 7) * 8;
      int byte = (h * 128 + rb * 2) ^ ((h & 7) << 4);
      uint4 ov = *(const uint4*)(Ow + byte);          // ds_read_b128
      int b = p0 >> 20, ij0 = (p0 & 1048575) + rb;
      *(uint4*)&rpe[((size_t)(b * 8 + h) << 20) + ij0] = ov;
    }
  }
}

// ---------------------------------------------------------------- GEMM ----
// C[M][N] = A[M][K] (bf16 rm) * Bt[N][K] (bf16, pre-transposed) + bias
enum { EPI_F32 = 0, EPI_GELU = 1, EPI_QKV = 2 };
#define BM 128
#define BN 128
#define BKK 64

template <int EPI>
__global__ __launch_bounds__(256, 2) void gemm_bt(
    const unsigned short* __restrict__ A, const unsigned short* __restrict__ Bt,
    const float* __restrict__ bias, void* __restrict__ O0, void* __restrict__ O1,
    void* __restrict__ O2, int M, int N, int K) {
  __shared__ unsigned short As[BM * BKK];
  __shared__ unsigned short Bs[BN * BKK];
  const int tid = threadIdx.x, lane = tid & 63, w = tid >> 6;
  const int wr = w >> 1, wc = w & 1;
  const int m0 = blockIdx.y * BM, n0 = blockIdx.x * BN;
  const int l15 = lane & 15, l4g = lane >> 4;

  f32x4 acc[4][4];
#pragma unroll
  for (int i = 0; i < 4; i++)
#pragma unroll
    for (int j = 0; j < 4; j++) acc[i][j] = (f32x4){0.f, 0.f, 0.f, 0.f};

  const int nkt = K / BKK;
  for (int kt = 0; kt < nkt; ++kt) {
#pragma unroll
    for (int it = 0; it < 4; ++it) {
      int c = it * 256 + tid;
      int row = c >> 3, c8 = (c & 7) * 8;
      load_lds16(A + (size_t)(m0 + row) * K + kt * BKK + c8, (char*)As + c * 16);
    }
#pragma unroll
    for (int it = 0; it < 4; ++it) {
      int c = it * 256 + tid;
      int row = c >> 3, c8 = (c & 7) * 8;
      load_lds16(Bt + (size_t)(n0 + row) * K + kt * BKK + c8, (char*)Bs + c * 16);
    }
    asm volatile("s_waitcnt vmcnt(0)" ::: "memory");
    __syncthreads();
#pragma unroll
    for (int kk = 0; kk < 2; ++kk) {
      bf16x8 af[4], bfv[4];
#pragma unroll
      for (int i = 0; i < 4; i++)
        af[i] = *(const bf16x8*)&As[(wr * 64 + i * 16 + l15) * BKK + kk * 32 + l4g * 8];
#pragma unroll
      for (int j = 0; j < 4; j++)
        bfv[j] = *(const bf16x8*)&Bs[(wc * 64 + j * 16 + l15) * BKK + kk * 32 + l4g * 8];
#pragma unroll
      for (int i = 0; i < 4; i++)
#pragma unroll
        for (int j = 0; j < 4; j++)
          acc[i][j] = __builtin_amdgcn_mfma_f32_16x16x32_bf16(af[i], bfv[j], acc[i][j], 0, 0, 0);
    }
    __syncthreads();
  }

#pragma unroll
  for (int i = 0; i < 4; i++) {
    int row = m0 + wr * 64 + i * 16 + l4g * 4;
#pragma unroll
    for (int j = 0; j < 4; j++) {
      int col = n0 + wc * 64 + j * 16 + l15;
      float bv = bias ? bias[col] : 0.f;
#pragma unroll
      for (int r = 0; r < 4; r++) {
        float v = acc[i][j][r] + bv;
        int rr = row + r;
        if (EPI == EPI_F32) {
          ((float*)O0)[(size_t)rr * N + col] = v;
        } else if (EPI == EPI_GELU) {
          float gv = 0.5f * v * (1.f + erff(v * 0.70710678118f));
          ((unsigned short*)O0)[(size_t)rr * N + col] = f2bf(gv);
        } else {  // QKV scatter
          int b = rr >> 10, n = rr & 1023;
          int d = col & 511, h = d >> 6, hd = d & 63;
          int bh = b * 8 + h;
          unsigned short bv16 = f2bf(v);
          if (col < 512)
            ((unsigned short*)O0)[((size_t)bh * 1024 + n) * 64 + hd] = bv16;
          else if (col < 1024)
            ((unsigned short*)O1)[((size_t)bh * 1024 + n) * 64 + hd] = bv16;
          else
            ((unsigned short*)O2)[((size_t)bh * 64 + hd) * 1024 + n] = bv16;
        }
      }
    }
  }
}

// ------------------------------------------------------------- attention --
// grid 256. Remapped so all 16 q-tiles of one bh share an XCD (L2 K/V reuse).
// Double-buffered staging (2-phase): stage next tile before compute.
__global__ __launch_bounds__(256) void attn_kernel(
    const unsigned short* __restrict__ Qh, const unsigned short* __restrict__ Kh,
    const unsigned short* __restrict__ VT, const unsigned short* __restrict__ rpe,
    unsigned short* __restrict__ AO) {
  __shared__ unsigned short Ks[2][64 * 64], Vs[2][64 * 64], Rs[2][64 * 64];
  __shared__ unsigned short Ps[4][16 * 64];
  const int tid = threadIdx.x, lane = tid & 63, w = tid >> 6;
  const int l15 = lane & 15, l4g = lane >> 4;
  const int bid = blockIdx.x;
  const int it = (bid >> 3) & 15;                    // q-tile
  const int bh = (bid & 7) | ((bid >> 7) << 3);      // same-bh -> same XCD
  const int i0 = it * 64;
  const unsigned short* Qb = Qh + (size_t)bh * SEQ * HDIM;
  const unsigned short* Kb = Kh + (size_t)bh * SEQ * HDIM;
  const unsigned short* Vb = VT + (size_t)bh * HDIM * SEQ;
  const unsigned short* Rb = rpe + ((size_t)bh << 20);

  bf16x8 qf[2];
#pragma unroll
  for (int kk = 0; kk < 2; kk++)
    qf[kk] = *(const bf16x8*)&Qb[(size_t)(i0 + w * 16 + l15) * 64 + kk * 32 + l4g * 8];

  f32x4 o[4];
#pragma unroll
  for (int i = 0; i < 4; i++) o[i] = (f32x4){0.f, 0.f, 0.f, 0.f};
  float m4[4], l4s[4];
#pragma unroll
  for (int r = 0; r < 4; r++) { m4[r] = -1e30f; l4s[r] = 0.f; }

  auto stage = [&](int buf, int jt) {
    int j0 = jt * 64;
#pragma unroll
    for (int itn = 0; itn < 2; ++itn) {
      int c = itn * 256 + tid, row = c >> 3, c8 = (c & 7) * 8;
      load_lds16(Kb + (size_t)(j0 + row) * 64 + c8, (char*)&Ks[buf][0] + c * 16);
      load_lds16(Vb + (size_t)row * SEQ + j0 + c8, (char*)&Vs[buf][0] + c * 16);
      load_lds16(Rb + (size_t)(i0 + row) * SEQ + j0 + c8, (char*)&Rs[buf][0] + c * 16);
    }
  };

  stage(0, 0);
  asm volatile("s_waitcnt vmcnt(0)" ::: "memory");
  __syncthreads();

  for (int jt = 0; jt < 16; ++jt) {
    const int cur = jt & 1;
    if (jt < 15) stage(cur ^ 1, jt + 1);

    f32x4 sa[4];
#pragma unroll
    for (int js = 0; js < 4; js++) sa[js] = (f32x4){0.f, 0.f, 0.f, 0.f};
#pragma unroll
    for (int kk = 0; kk < 2; kk++) {
#pragma unroll
      for (int js = 0; js < 4; js++) {
        bf16x8 kb = *(const bf16x8*)&Ks[cur][(js * 16 + l15) * 64 + kk * 32 + l4g * 8];
        sa[js] = __builtin_amdgcn_mfma_f32_16x16x32_bf16(qf[kk], kb, sa[js], 0, 0, 0);
      }
    }
    // scores + rpe, row max
    float p[4][4], mx[4];
#pragma unroll
    for (int r = 0; r < 4; r++) mx[r] = -1e30f;
#pragma unroll
    for (int js = 0; js < 4; js++)
#pragma unroll
      for (int r = 0; r < 4; r++) {
        float rv = bf2f(Rs[cur][(w * 16 + l4g * 4 + r) * 64 + js * 16 + l15]);
        float s = sa[js][r] * 0.125f + rv;
        p[js][r] = s;
        mx[r] = fmaxf(mx[r], s);
      }
#pragma unroll
    for (int off = 1; off < 16; off <<= 1)
#pragma unroll
      for (int r = 0; r < 4; r++) mx[r] = fmaxf(mx[r], __shfl_xor(mx[r], off));
    float al[4], sm[4];
#pragma unroll
    for (int r = 0; r < 4; r++) {
      float nm = fmaxf(m4[r], mx[r]);
      al[r] = __expf(m4[r] - nm);
      m4[r] = nm;
      sm[r] = 0.f;
    }
#pragma unroll
    for (int js = 0; js < 4; js++)
#pragma unroll
      for (int r = 0; r < 4; r++) {
        float e = __expf(p[js][r] - m4[r]);
        p[js][r] = e;
        sm[r] += e;
      }
#pragma unroll
    for (int off = 1; off < 16; off <<= 1)
#pragma unroll
      for (int r = 0; r < 4; r++) sm[r] += __shfl_xor(sm[r], off);
#pragma unroll
    for (int r = 0; r < 4; r++) l4s[r] = l4s[r] * al[r] + sm[r];
#pragma unroll
    for (int hdf = 0; hdf < 4; hdf++)
#pragma unroll
      for (int r = 0; r < 4; r++) o[hdf][r] *= al[r];
    // P -> LDS (wave-private) for A-fragment layout
#pragma unroll
    for (int js = 0; js < 4; js++)
#pragma unroll
      for (int r = 0; r < 4; r++)
        Ps[w][(l4g * 4 + r) * 64 + js * 16 + l15] = f2bf(p[js][r]);
    // PV
#pragma unroll
    for (int kk = 0; kk < 2; kk++) {
      bf16x8 pf = *(const bf16x8*)&Ps[w][l15 * 64 + kk * 32 + l4g * 8];
#pragma unroll
      for (int hdf = 0; hdf < 4; hdf++) {
        bf16x8 vb = *(const bf16x8*)&Vs[cur][(hdf * 16 + l15) * 64 + kk * 32 + l4g * 8];
        o[hdf] = __builtin_amdgcn_mfma_f32_16x16x32_bf16(pf, vb, o[hdf], 0, 0, 0);
      }
    }
    asm volatile("s_waitcnt vmcnt(0)" ::: "memory");
    __syncthreads();
  }
  const int b = bh >> 3, h = bh & 7;
#pragma unroll
  for (int hdf = 0; hdf < 4; hdf++)
#pragma unroll
    for (int r = 0; r < 4; r++) {
      float v = o[hdf][r] / l4s[r];
      int n = i0 + w * 16 + l4g * 4 + r;
      AO[((size_t)b * SEQ + n) * DMODEL + h * 64 + hdf * 16 + l15] = f2bf(v);
    }
}

// ---------------------------------------------------------------- LN ------
__global__ __launch_bounds__(256) void ln_kernel(
    const float* __restrict__ a, const float* __restrict__ res,
    const float* __restrict__ g, const float* __restrict__ be,
    float* __restrict__ outf, unsigned short* __restrict__ outb) {
  const int row = blockIdx.x, t = threadIdx.x;
  const float* pa = a + (size_t)row * DMODEL;
  const float* pb = res + (size_t)row * DMODEL;
  float v0 = pa[t] + pb[t];
  float v1 = pa[t + 256] + pb[t + 256];
  float s = v0 + v1, sq = v0 * v0 + v1 * v1;
#pragma unroll
  for (int off = 1; off < 64; off <<= 1) {
    s += __shfl_xor(s, off);
    sq += __shfl_xor(sq, off);
  }
  __shared__ float ls[4], lq[4];
  int w = t >> 6, lane = t & 63;
  if (lane == 0) { ls[w] = s; lq[w] = sq; }
  __syncthreads();
  s = ls[0] + ls[1] + ls[2] + ls[3];
  sq = lq[0] + lq[1] + lq[2] + lq[3];
  float mu = s * (1.f / DMODEL);
  float var = sq * (1.f / DMODEL) - mu * mu;
  float rs = rsqrtf(var + 1e-5f);
  float y0 = (v0 - mu) * rs * g[t] + be[t];
  float y1v = (v1 - mu) * rs * g[t + 256] + be[t + 256];
  outf[(size_t)row * DMODEL + t] = y0;
  outf[(size_t)row * DMODEL + t + 256] = y1v;
  if (outb) {
    outb[(size_t)row * DMODEL + t] = f2bf(y0);
    outb[(size_t)row * DMODEL + t + 256] = f2bf(y1v);
  }
}

// ---------------------------------------------------------------- launch --
extern "C" void kernel_launch(void* const* d_in, const int* in_sizes, int n_in,
                              void* d_out, int out_size, void* d_ws, size_t ws_size,
                              hipStream_t stream) {
  const float* x   = (const float*)d_in[0];
  const float* rel = (const float*)d_in[1];
  const float* Wq  = (const float*)d_in[2];
  const float* bq  = (const float*)d_in[3];
  const float* Wk  = (const float*)d_in[4];
  const float* bk  = (const float*)d_in[5];
  const float* Wv  = (const float*)d_in[6];
  const float* bv  = (const float*)d_in[7];
  const float* Wo  = (const float*)d_in[8];
  const float* bo  = (const float*)d_in[9];
  const float* R1  = (const float*)d_in[10];
  const float* rb1 = (const float*)d_in[11];
  const float* R2  = (const float*)d_in[12];
  const float* rb2 = (const float*)d_in[13];
  const float* g1  = (const float*)d_in[14];
  const float* b1  = (const float*)d_in[15];
  const float* g2  = (const float*)d_in[16];
  const float* b2  = (const float*)d_in[17];
  const float* F1  = (const float*)d_in[18];
  const float* fb1 = (const float*)d_in[19];
  const float* F2  = (const float*)d_in[20];
  const float* fb2 = (const float*)d_in[21];

  char* p = (char*)d_ws;
  auto alloc = [&](size_t bytes) {
    char* r = p;
    p += (bytes + 255) & ~(size_t)255;
    return r;
  };
  unsigned short* xb   = (unsigned short*)alloc((size_t)2048 * 512 * 2);
  unsigned short* qkvT = (unsigned short*)alloc((size_t)1536 * 512 * 2);
  float*          bqkv = (float*)alloc(1536 * 4);
  unsigned short* WoT  = (unsigned short*)alloc((size_t)512 * 512 * 2);
  unsigned short* F1T  = (unsigned short*)alloc((size_t)2048 * 512 * 2);
  unsigned short* F2T  = (unsigned short*)alloc((size_t)512 * 2048 * 2);
  unsigned short* Qhp  = (unsigned short*)alloc((size_t)BH * SEQ * HDIM * 2);
  unsigned short* Khp  = (unsigned short*)alloc((size_t)BH * SEQ * HDIM * 2);
  unsigned short* VTp  = (unsigned short*)alloc((size_t)BH * HDIM * SEQ * 2);
  unsigned short* rpep = (unsigned short*)alloc((size_t)BH * SEQ * SEQ * 2);   // 32MB
  unsigned short* attO = (unsigned short*)alloc((size_t)2048 * 512 * 2);
  float*          t1   = (float*)alloc((size_t)2048 * 512 * 4);
  float*          y1   = (float*)alloc((size_t)2048 * 512 * 4);
  unsigned short* y1b  = (unsigned short*)alloc((size_t)2048 * 512 * 2);
  float*          t2   = t1;                     // t1 dead after LN1
  unsigned short* hbuf = rpep;                   // rpe dead after attention

  prep_misc<<<1024, 256, 0, stream>>>(x, bq, bk, bv, xb, bqkv);
  prep_weights<<<3072, dim3(32, 8), 0, stream>>>(Wq, Wk, Wv, Wo, F1, F2,
                                                 qkvT, WoT, F1T, F2T);
  rpe_mfma<<<1024, 256, 0, stream>>>(rel, R1, rb1, R2, rb2, rpep);

  gemm_bt<EPI_QKV><<<dim3(12, 16), 256, 0, stream>>>(xb, qkvT, bqkv, Qhp, Khp, VTp,
                                                     2048, 1536, 512);
  attn_kernel<<<256, 256, 0, stream>>>(Qhp, Khp, VTp, rpep, attO);

  gemm_bt<EPI_F32><<<dim3(4, 16), 256, 0, stream>>>(attO, WoT, bo, t1, nullptr, nullptr,
                                                    2048, 512, 512);
  ln_kernel<<<2048, 256, 0, stream>>>(x, t1, g1, b1, y1, y1b);

  gemm_bt<EPI_GELU><<<dim3(16, 16), 256, 0, stream>>>(y1b, F1T, fb1, hbuf, nullptr, nullptr,
                                                      2048, 2048, 512);
  gemm_bt<EPI_F32><<<dim3(4, 16), 256, 0, stream>>>(hbuf, F2T, fb2, t2, nullptr, nullptr,
                                                    2048, 512, 2048);
  ln_kernel<<<2048, 256, 0, stream>>>(y1, t2, g2, b2, (float*)d_out, nullptr);
}

// Round 4
// 262.108 us; speedup vs baseline: 1.2374x; 1.1907x over previous
//
#include <hip/hip_runtime.h>
#include <math.h>

// Problem constants
#define BATCH 2
#define SEQ   1024
#define DMODEL 512
#define NHEAD 8
#define HDIM  64
#define FFND  2048
#define BH    (BATCH*NHEAD)   // 16

typedef float  f32x4  __attribute__((ext_vector_type(4)));
typedef __bf16 bf16x8 __attribute__((ext_vector_type(8)));

__device__ __forceinline__ unsigned short f2bf(float f) {
  union { float f; unsigned u; } x; x.f = f;
  unsigned r = x.u + 0x7fffu + ((x.u >> 16) & 1u);
  return (unsigned short)(r >> 16);
}
__device__ __forceinline__ float bf2f(unsigned short h) {
  union { unsigned u; float f; } x; x.u = ((unsigned)h) << 16;
  return x.f;
}
__device__ __forceinline__ unsigned pk2(float a, float b) {
  return (unsigned)f2bf(a) | ((unsigned)f2bf(b) << 16);
}

__device__ __forceinline__ void load_lds16(const void* g, void* l) {
  __builtin_amdgcn_global_load_lds((const __attribute__((address_space(1))) void*)g,
                                   (__attribute__((address_space(3))) void*)l, 16, 0, 0);
}

// ---------------------------------------------------------------- prep ----
__global__ __launch_bounds__(256) void prep_misc(
    const float* __restrict__ x, const float* __restrict__ bq,
    const float* __restrict__ bk, const float* __restrict__ bv,
    unsigned short* __restrict__ xb, float* __restrict__ bqkv) {
  int gid = blockIdx.x * 256 + threadIdx.x;       // 262144 threads x 4 els
  float4 v = ((const float4*)x)[gid];
  ushort4 s;
  s.x = f2bf(v.x); s.y = f2bf(v.y); s.z = f2bf(v.z); s.w = f2bf(v.w);
  ((ushort4*)xb)[gid] = s;
  if (gid < 1536)
    bqkv[gid] = gid < 512 ? bq[gid] : (gid < 1024 ? bk[gid - 512] : bv[gid - 1024]);
}

// all weight transposes fused: src f32 [R][C] -> dst bf16 [C][R]. block (32,8).
__global__ __launch_bounds__(256) void prep_weights(
    const float* __restrict__ Wq, const float* __restrict__ Wk,
    const float* __restrict__ Wv, const float* __restrict__ Wo,
    const float* __restrict__ F1, const float* __restrict__ F2,
    unsigned short* __restrict__ qkvT, unsigned short* __restrict__ WoT,
    unsigned short* __restrict__ F1T, unsigned short* __restrict__ F2T) {
  __shared__ float t[32][33];
  int bid = blockIdx.x;
  const float* src; unsigned short* dst; int R, C, tx, ty;
  if (bid < 1024) {
    int m = bid >> 8;
    src = m == 0 ? Wq : m == 1 ? Wk : m == 2 ? Wv : Wo;
    dst = m < 3 ? qkvT + m * 512 * 512 : WoT;
    R = 512; C = 512; int u = bid & 255; tx = u & 15; ty = u >> 4;
  } else if (bid < 2048) {
    src = F1; dst = F1T; R = 512; C = 2048;
    int u = bid - 1024; tx = u & 63; ty = u >> 6;
  } else {
    src = F2; dst = F2T; R = 2048; C = 512;
    int u = bid - 2048; tx = u & 15; ty = u >> 4;
  }
  int c0 = tx * 32, r0 = ty * 32;
  int x_ = threadIdx.x, y_ = threadIdx.y;
#pragma unroll
  for (int i = 0; i < 4; i++)
    t[y_ + i * 8][x_] = src[(size_t)(r0 + y_ + i * 8) * C + c0 + x_];
  __syncthreads();
#pragma unroll
  for (int i = 0; i < 4; i++)
    dst[(size_t)(c0 + y_ + i * 8) * R + r0 + x_] = f2bf(t[x_][y_ + i * 8]);
}

// ---------------------------------------------------------------- RPE -----
__global__ __launch_bounds__(256) void rpe_mfma(
    const float* __restrict__ rel, const float* __restrict__ R1,
    const float* __restrict__ rb1, const float* __restrict__ R2,
    const float* __restrict__ rb2, unsigned short* __restrict__ rpe) {
  __shared__ unsigned short Hs[4][64 * 64];
  __shared__ unsigned short Os[4][8 * 64];
  const int tid = threadIdx.x, lane = tid & 63, w = tid >> 6;
  const int l15 = lane & 15, l4g = lane >> 4;
  char* Hw = (char*)&Hs[w][0];
  char* Ow = (char*)&Os[w][0];

  bf16x8 a1[4];
#pragma unroll
  for (int mt = 0; mt < 4; mt++) {
    bf16x8 z = {};
    if (l4g == 0) {
      int m = mt * 16 + l15;
      z[0] = (__bf16)R1[0 * 64 + m];
      z[1] = (__bf16)R1[1 * 64 + m];
      z[2] = (__bf16)R1[2 * 64 + m];
      z[3] = (__bf16)R1[3 * 64 + m];
    }
    a1[mt] = z;
  }
  float rb1v[4][4];
#pragma unroll
  for (int mt = 0; mt < 4; mt++)
#pragma unroll
    for (int r = 0; r < 4; r++) rb1v[mt][r] = rb1[mt * 16 + l4g * 4 + r];
  bf16x8 b2f[2];
#pragma unroll
  for (int ks = 0; ks < 2; ks++) {
    bf16x8 z = {};
    if (l15 < 8) {
#pragma unroll
      for (int j = 0; j < 8; j++)
        z[j] = (__bf16)R2[(ks * 32 + l4g * 8 + j) * 8 + l15];
    }
    b2f[ks] = z;
  }
  float rb2v = (l15 < 8) ? rb2[l15] : 0.f;

  const int nwaves = gridDim.x * 4;            // 4096
  const int wgid = blockIdx.x * 4 + w;
  for (int itr = 0; itr < 8; itr++) {
    int p0 = (wgid + itr * nwaves) * 64;
    bf16x8 b1[4];
#pragma unroll
    for (int nt = 0; nt < 4; nt++) {
      bf16x8 z = {};
      if (l4g == 0) {
        float4 rv = *(const float4*)&rel[(size_t)(p0 + nt * 16 + l15) * 4];
        z[0] = (__bf16)rv.x; z[1] = (__bf16)rv.y;
        z[2] = (__bf16)rv.z; z[3] = (__bf16)rv.w;
      }
      b1[nt] = z;
    }
#pragma unroll
    for (int nt = 0; nt < 4; nt++) {
#pragma unroll
      for (int mt = 0; mt < 4; mt++) {
        f32x4 hacc = __builtin_amdgcn_mfma_f32_16x16x32_bf16(
            a1[mt], b1[nt], (f32x4){0.f, 0.f, 0.f, 0.f}, 0, 0, 0);
        int row = nt * 16 + l15;
        int dim0 = mt * 16 + l4g * 4;
        float v0 = fmaxf(hacc[0] + rb1v[mt][0], 0.f);
        float v1 = fmaxf(hacc[1] + rb1v[mt][1], 0.f);
        float v2 = fmaxf(hacc[2] + rb1v[mt][2], 0.f);
        float v3 = fmaxf(hacc[3] + rb1v[mt][3], 0.f);
        int byte = (row * 128 + dim0 * 2) ^ ((row & 7) << 4);
        uint2 pk; pk.x = pk2(v0, v1); pk.y = pk2(v2, v3);
        *(uint2*)(Hw + byte) = pk;
      }
    }
    f32x4 acc2[4];
#pragma unroll
    for (int mt = 0; mt < 4; mt++) acc2[mt] = (f32x4){0.f, 0.f, 0.f, 0.f};
#pragma unroll
    for (int ks = 0; ks < 2; ks++) {
#pragma unroll
      for (int mt = 0; mt < 4; mt++) {
        int row = mt * 16 + l15;
        int byte = (row * 128 + (ks * 32 + l4g * 8) * 2) ^ ((l15 & 7) << 4);
        bf16x8 af = *(const bf16x8*)(Hw + byte);
        acc2[mt] = __builtin_amdgcn_mfma_f32_16x16x32_bf16(af, b2f[ks], acc2[mt], 0, 0, 0);
      }
    }
#pragma unroll
    for (int mt = 0; mt < 4; mt++) {
      if (l15 < 8) {
        int byte = (l15 * 128 + (mt * 16 + l4g * 4) * 2) ^ ((l15 & 7) << 4);
        uint2 pk;
        pk.x = pk2(acc2[mt][0] + rb2v, acc2[mt][1] + rb2v);
        pk.y = pk2(acc2[mt][2] + rb2v, acc2[mt][3] + rb2v);
        *(uint2*)(Ow + byte) = pk;
      }
    }
    {
      int h = lane >> 3, rb = (lane & 7) * 8;
      int byte = (h * 128 + rb * 2) ^ ((h & 7) << 4);
      uint4 ov = *(const uint4*)(Ow + byte);
      int b = p0 >> 20, ij0 = (p0 & 1048575) + rb;
      *(uint4*)&rpe[((size_t)(b * 8 + h) << 20) + ij0] = ov;
    }
  }
}

// ---------------------------------------------------------------- GEMM ----
// C[M][N] = A[M][K] (bf16 rm) * Bt[N][K] (bf16 pre-transposed) + bias.
// Double-buffered LDS, XOR-swizzled (pre-swizzled global src + swizzled read).
// 2x2 waves; wave tile (WM*16) x (WN*16); BMt=2*WM*16, BNt=2*WN*16.
enum { EPI_F32 = 0, EPI_GELU = 1, EPI_QKV = 2 };

template <int EPI, int BMt, int BNt, int WM, int WN>
__global__ __launch_bounds__(256) void gemm_bt(
    const unsigned short* __restrict__ A, const unsigned short* __restrict__ Bt,
    const float* __restrict__ bias, void* __restrict__ O0, void* __restrict__ O1,
    void* __restrict__ O2, int M, int N, int K) {
  __shared__ unsigned short As[2][BMt * 64];
  __shared__ unsigned short Bs[2][BNt * 64];
  const int tid = threadIdx.x, lane = tid & 63, w = tid >> 6;
  const int wr = w >> 1, wc = w & 1;
  const int m0 = blockIdx.y * BMt, n0 = blockIdx.x * BNt;
  const int l15 = lane & 15, l4g = lane >> 4;

  f32x4 acc[WM][WN];
#pragma unroll
  for (int i = 0; i < WM; i++)
#pragma unroll
    for (int j = 0; j < WN; j++) acc[i][j] = (f32x4){0.f, 0.f, 0.f, 0.f};

  auto stage = [&](int buf, int kt) {
#pragma unroll
    for (int it = 0; it < BMt / 32; ++it) {
      int c = it * 256 + tid, row = c >> 3;
      int s16 = (c & 7) ^ (row & 7);
      load_lds16(A + (size_t)(m0 + row) * K + kt * 64 + s16 * 8,
                 (char*)&As[buf][0] + c * 16);
    }
#pragma unroll
    for (int it = 0; it < BNt / 32; ++it) {
      int c = it * 256 + tid, row = c >> 3;
      int s16 = (c & 7) ^ (row & 7);
      load_lds16(Bt + (size_t)(n0 + row) * K + kt * 64 + s16 * 8,
                 (char*)&Bs[buf][0] + c * 16);
    }
  };

  const int nkt = K / 64;
  stage(0, 0);
  asm volatile("s_waitcnt vmcnt(0)" ::: "memory");
  __syncthreads();

  for (int kt = 0; kt < nkt; ++kt) {
    const int cur = kt & 1;
    if (kt + 1 < nkt) stage(cur ^ 1, kt + 1);
#pragma unroll
    for (int kk = 0; kk < 2; ++kk) {
      bf16x8 af[WM], bfv[WN];
#pragma unroll
      for (int i = 0; i < WM; i++) {
        int row = wr * (WM * 16) + i * 16 + l15;
        af[i] = *(const bf16x8*)((char*)&As[cur][0] + row * 128 +
                                 (((kk * 4 + l4g) ^ (row & 7)) << 4));
      }
#pragma unroll
      for (int j = 0; j < WN; j++) {
        int row = wc * (WN * 16) + j * 16 + l15;
        bfv[j] = *(const bf16x8*)((char*)&Bs[cur][0] + row * 128 +
                                  (((kk * 4 + l4g) ^ (row & 7)) << 4));
      }
#pragma unroll
      for (int i = 0; i < WM; i++)
#pragma unroll
        for (int j = 0; j < WN; j++)
          acc[i][j] = __builtin_amdgcn_mfma_f32_16x16x32_bf16(af[i], bfv[j], acc[i][j], 0, 0, 0);
    }
    asm volatile("s_waitcnt vmcnt(0)" ::: "memory");
    __syncthreads();
  }

#pragma unroll
  for (int i = 0; i < WM; i++) {
    int row = m0 + wr * (WM * 16) + i * 16 + l4g * 4;
#pragma unroll
    for (int j = 0; j < WN; j++) {
      int col = n0 + wc * (WN * 16) + j * 16 + l15;
      float bv = bias ? bias[col] : 0.f;
#pragma unroll
      for (int r = 0; r < 4; r++) {
        float v = acc[i][j][r] + bv;
        int rr = row + r;
        if (EPI == EPI_F32) {
          ((float*)O0)[(size_t)rr * N + col] = v;
        } else if (EPI == EPI_GELU) {
          float gv = 0.5f * v * (1.f + erff(v * 0.70710678118f));
          ((unsigned short*)O0)[(size_t)rr * N + col] = f2bf(gv);
        } else {  // QKV scatter
          int b = rr >> 10, n = rr & 1023;
          int d = col & 511, h = d >> 6, hd = d & 63;
          int bh = b * 8 + h;
          unsigned short bv16 = f2bf(v);
          if (col < 512)
            ((unsigned short*)O0)[((size_t)bh * 1024 + n) * 64 + hd] = bv16;
          else if (col < 1024)
            ((unsigned short*)O1)[((size_t)bh * 1024 + n) * 64 + hd] = bv16;
          else
            ((unsigned short*)O2)[((size_t)bh * 64 + hd) * 1024 + n] = bv16;
        }
      }
    }
  }
}

// ------------------------------------------------------------- attention --
// grid 256, double-buffered, XOR-swizzled LDS tiles.
__global__ __launch_bounds__(256) void attn_kernel(
    const unsigned short* __restrict__ Qh, const unsigned short* __restrict__ Kh,
    const unsigned short* __restrict__ VT, const unsigned short* __restrict__ rpe,
    unsigned short* __restrict__ AO) {
  __shared__ unsigned short Ks[2][64 * 64], Vs[2][64 * 64], Rs[2][64 * 64];
  __shared__ unsigned short Ps[4][16 * 64];
  const int tid = threadIdx.x, lane = tid & 63, w = tid >> 6;
  const int l15 = lane & 15, l4g = lane >> 4;
  const int bid = blockIdx.x;
  const int it = (bid >> 3) & 15;
  const int bh = (bid & 7) | ((bid >> 7) << 3);
  const int i0 = it * 64;
  const unsigned short* Qb = Qh + (size_t)bh * SEQ * HDIM;
  const unsigned short* Kb = Kh + (size_t)bh * SEQ * HDIM;
  const unsigned short* Vb = VT + (size_t)bh * HDIM * SEQ;
  const unsigned short* Rb = rpe + ((size_t)bh << 20);

  bf16x8 qf[2];
#pragma unroll
  for (int kk = 0; kk < 2; kk++)
    qf[kk] = *(const bf16x8*)&Qb[(size_t)(i0 + w * 16 + l15) * 64 + kk * 32 + l4g * 8];

  f32x4 o[4];
#pragma unroll
  for (int i = 0; i < 4; i++) o[i] = (f32x4){0.f, 0.f, 0.f, 0.f};
  float m4[4], l4s[4];
#pragma unroll
  for (int r = 0; r < 4; r++) { m4[r] = -1e30f; l4s[r] = 0.f; }

  auto stage = [&](int buf, int jt) {
    int j0 = jt * 64;
#pragma unroll
    for (int itn = 0; itn < 2; ++itn) {
      int c = itn * 256 + tid, row = c >> 3;
      int s8 = ((c & 7) ^ (row & 7)) * 8;
      load_lds16(Kb + (size_t)(j0 + row) * 64 + s8, (char*)&Ks[buf][0] + c * 16);
      load_lds16(Vb + (size_t)row * SEQ + j0 + s8, (char*)&Vs[buf][0] + c * 16);
      load_lds16(Rb + (size_t)(i0 + row) * SEQ + j0 + s8, (char*)&Rs[buf][0] + c * 16);
    }
  };

  stage(0, 0);
  asm volatile("s_waitcnt vmcnt(0)" ::: "memory");
  __syncthreads();

  for (int jt = 0; jt < 16; ++jt) {
    const int cur = jt & 1;
    if (jt < 15) stage(cur ^ 1, jt + 1);

    f32x4 sa[4];
#pragma unroll
    for (int js = 0; js < 4; js++) sa[js] = (f32x4){0.f, 0.f, 0.f, 0.f};
#pragma unroll
    for (int kk = 0; kk < 2; kk++) {
#pragma unroll
      for (int js = 0; js < 4; js++) {
        int row = js * 16 + l15;
        bf16x8 kb = *(const bf16x8*)((char*)&Ks[cur][0] + row * 128 +
                                     (((kk * 4 + l4g) ^ (row & 7)) << 4));
        sa[js] = __builtin_amdgcn_mfma_f32_16x16x32_bf16(qf[kk], kb, sa[js], 0, 0, 0);
      }
    }
    float p[4][4], mx[4];
#pragma unroll
    for (int r = 0; r < 4; r++) mx[r] = -1e30f;
#pragma unroll
    for (int js = 0; js < 4; js++)
#pragma unroll
      for (int r = 0; r < 4; r++) {
        int row = w * 16 + l4g * 4 + r;
        int byte = row * 128 + ((((js * 2) + (l15 >> 3)) ^ (row & 7)) << 4) + ((l15 & 7) << 1);
        float rv = bf2f(*(const unsigned short*)((const char*)&Rs[cur][0] + byte));
        float s = sa[js][r] * 0.125f + rv;
        p[js][r] = s;
        mx[r] = fmaxf(mx[r], s);
      }
#pragma unroll
    for (int off = 1; off < 16; off <<= 1)
#pragma unroll
      for (int r = 0; r < 4; r++) mx[r] = fmaxf(mx[r], __shfl_xor(mx[r], off));
    float al[4], sm[4];
#pragma unroll
    for (int r = 0; r < 4; r++) {
      float nm = fmaxf(m4[r], mx[r]);
      al[r] = __expf(m4[r] - nm);
      m4[r] = nm;
      sm[r] = 0.f;
    }
#pragma unroll
    for (int js = 0; js < 4; js++)
#pragma unroll
      for (int r = 0; r < 4; r++) {
        float e = __expf(p[js][r] - m4[r]);
        p[js][r] = e;
        sm[r] += e;
      }
#pragma unroll
    for (int off = 1; off < 16; off <<= 1)
#pragma unroll
      for (int r = 0; r < 4; r++) sm[r] += __shfl_xor(sm[r], off);
#pragma unroll
    for (int r = 0; r < 4; r++) l4s[r] = l4s[r] * al[r] + sm[r];
#pragma unroll
    for (int hdf = 0; hdf < 4; hdf++)
#pragma unroll
      for (int r = 0; r < 4; r++) o[hdf][r] *= al[r];
    // P -> LDS (wave-private, swizzled)
#pragma unroll
    for (int js = 0; js < 4; js++)
#pragma unroll
      for (int r = 0; r < 4; r++) {
        int row = l4g * 4 + r;
        int byte = row * 128 + ((((js * 2) + (l15 >> 3)) ^ (row & 7)) << 4) + ((l15 & 7) << 1);
        *(unsigned short*)((char*)&Ps[w][0] + byte) = f2bf(p[js][r]);
      }
    // PV
#pragma unroll
    for (int kk = 0; kk < 2; kk++) {
      bf16x8 pf = *(const bf16x8*)((char*)&Ps[w][0] + l15 * 128 +
                                   (((kk * 4 + l4g) ^ (l15 & 7)) << 4));
#pragma unroll
      for (int hdf = 0; hdf < 4; hdf++) {
        int row = hdf * 16 + l15;
        bf16x8 vb = *(const bf16x8*)((char*)&Vs[cur][0] + row * 128 +
                                     (((kk * 4 + l4g) ^ (row & 7)) << 4));
        o[hdf] = __builtin_amdgcn_mfma_f32_16x16x32_bf16(pf, vb, o[hdf], 0, 0, 0);
      }
    }
    asm volatile("s_waitcnt vmcnt(0)" ::: "memory");
    __syncthreads();
  }
  const int b = bh >> 3, h = bh & 7;
#pragma unroll
  for (int hdf = 0; hdf < 4; hdf++)
#pragma unroll
    for (int r = 0; r < 4; r++) {
      float v = o[hdf][r] / l4s[r];
      int n = i0 + w * 16 + l4g * 4 + r;
      AO[((size_t)b * SEQ + n) * DMODEL + h * 64 + hdf * 16 + l15] = f2bf(v);
    }
}

// ---------------------------------------------------------------- LN ------
__global__ __launch_bounds__(256) void ln_kernel(
    const float* __restrict__ a, const float* __restrict__ res,
    const float* __restrict__ g, const float* __restrict__ be,
    float* __restrict__ outf, unsigned short* __restrict__ outb) {
  const int row = blockIdx.x, t = threadIdx.x;
  const float* pa = a + (size_t)row * DMODEL;
  const float* pb = res + (size_t)row * DMODEL;
  float v0 = pa[t] + pb[t];
  float v1 = pa[t + 256] + pb[t + 256];
  float s = v0 + v1, sq = v0 * v0 + v1 * v1;
#pragma unroll
  for (int off = 1; off < 64; off <<= 1) {
    s += __shfl_xor(s, off);
    sq += __shfl_xor(sq, off);
  }
  __shared__ float ls[4], lq[4];
  int w = t >> 6, lane = t & 63;
  if (lane == 0) { ls[w] = s; lq[w] = sq; }
  __syncthreads();
  s = ls[0] + ls[1] + ls[2] + ls[3];
  sq = lq[0] + lq[1] + lq[2] + lq[3];
  float mu = s * (1.f / DMODEL);
  float var = sq * (1.f / DMODEL) - mu * mu;
  float rs = rsqrtf(var + 1e-5f);
  float y0 = (v0 - mu) * rs * g[t] + be[t];
  float y1v = (v1 - mu) * rs * g[t + 256] + be[t + 256];
  outf[(size_t)row * DMODEL + t] = y0;
  outf[(size_t)row * DMODEL + t + 256] = y1v;
  if (outb) {
    outb[(size_t)row * DMODEL + t] = f2bf(y0);
    outb[(size_t)row * DMODEL + t + 256] = f2bf(y1v);
  }
}

// ---------------------------------------------------------------- launch --
extern "C" void kernel_launch(void* const* d_in, const int* in_sizes, int n_in,
                              void* d_out, int out_size, void* d_ws, size_t ws_size,
                              hipStream_t stream) {
  const float* x   = (const float*)d_in[0];
  const float* rel = (const float*)d_in[1];
  const float* Wq  = (const float*)d_in[2];
  const float* bq  = (const float*)d_in[3];
  const float* Wk  = (const float*)d_in[4];
  const float* bk  = (const float*)d_in[5];
  const float* Wv  = (const float*)d_in[6];
  const float* bv  = (const float*)d_in[7];
  const float* Wo  = (const float*)d_in[8];
  const float* bo  = (const float*)d_in[9];
  const float* R1  = (const float*)d_in[10];
  const float* rb1 = (const float*)d_in[11];
  const float* R2  = (const float*)d_in[12];
  const float* rb2 = (const float*)d_in[13];
  const float* g1  = (const float*)d_in[14];
  const float* b1  = (const float*)d_in[15];
  const float* g2  = (const float*)d_in[16];
  const float* b2  = (const float*)d_in[17];
  const float* F1  = (const float*)d_in[18];
  const float* fb1 = (const float*)d_in[19];
  const float* F2  = (const float*)d_in[20];
  const float* fb2 = (const float*)d_in[21];

  char* p = (char*)d_ws;
  auto alloc = [&](size_t bytes) {
    char* r = p;
    p += (bytes + 255) & ~(size_t)255;
    return r;
  };
  unsigned short* xb   = (unsigned short*)alloc((size_t)2048 * 512 * 2);
  unsigned short* qkvT = (unsigned short*)alloc((size_t)1536 * 512 * 2);
  float*          bqkv = (float*)alloc(1536 * 4);
  unsigned short* WoT  = (unsigned short*)alloc((size_t)512 * 512 * 2);
  unsigned short* F1T  = (unsigned short*)alloc((size_t)2048 * 512 * 2);
  unsigned short* F2T  = (unsigned short*)alloc((size_t)512 * 2048 * 2);
  unsigned short* Qhp  = (unsigned short*)alloc((size_t)BH * SEQ * HDIM * 2);
  unsigned short* Khp  = (unsigned short*)alloc((size_t)BH * SEQ * HDIM * 2);
  unsigned short* VTp  = (unsigned short*)alloc((size_t)BH * HDIM * SEQ * 2);
  unsigned short* rpep = (unsigned short*)alloc((size_t)BH * SEQ * SEQ * 2);   // 32MB
  unsigned short* attO = (unsigned short*)alloc((size_t)2048 * 512 * 2);
  float*          t1   = (float*)alloc((size_t)2048 * 512 * 4);
  float*          y1   = (float*)alloc((size_t)2048 * 512 * 4);
  unsigned short* y1b  = (unsigned short*)alloc((size_t)2048 * 512 * 2);
  float*          t2   = t1;                     // t1 dead after LN1
  unsigned short* hbuf = rpep;                   // rpe dead after attention

  prep_misc<<<1024, 256, 0, stream>>>(x, bq, bk, bv, xb, bqkv);
  prep_weights<<<3072, dim3(32, 8), 0, stream>>>(Wq, Wk, Wv, Wo, F1, F2,
                                                 qkvT, WoT, F1T, F2T);
  rpe_mfma<<<1024, 256, 0, stream>>>(rel, R1, rb1, R2, rb2, rpep);

  // QKV: 128x64 tiles -> 384 blocks
  gemm_bt<EPI_QKV, 128, 64, 4, 2><<<dim3(24, 16), 256, 0, stream>>>(
      xb, qkvT, bqkv, Qhp, Khp, VTp, 2048, 1536, 512);
  attn_kernel<<<256, 256, 0, stream>>>(Qhp, Khp, VTp, rpep, attO);

  // Wo: 64x64 tiles -> 256 blocks
  gemm_bt<EPI_F32, 64, 64, 2, 2><<<dim3(8, 32), 256, 0, stream>>>(
      attO, WoT, bo, t1, nullptr, nullptr, 2048, 512, 512);
  ln_kernel<<<2048, 256, 0, stream>>>(x, t1, g1, b1, y1, y1b);

  // FFN1: 128x64 tiles -> 512 blocks
  gemm_bt<EPI_GELU, 128, 64, 4, 2><<<dim3(32, 16), 256, 0, stream>>>(
      y1b, F1T, fb1, hbuf, nullptr, nullptr, 2048, 2048, 512);
  // FFN2: 64x64 tiles -> 256 blocks
  gemm_bt<EPI_F32, 64, 64, 2, 2><<<dim3(8, 32), 256, 0, stream>>>(
      hbuf, F2T, fb2, t2, nullptr, nullptr, 2048, 512, 2048);
  ln_kernel<<<2048, 256, 0, stream>>>(y1, t2, g2, b2, (float*)d_out, nullptr);
}

// Round 5
// 251.348 us; speedup vs baseline: 1.2903x; 1.0428x over previous
//
#include <hip/hip_runtime.h>
#include <math.h>

// Problem constants
#define BATCH 2
#define SEQ   1024
#define DMODEL 512
#define NHEAD 8
#define HDIM  64
#define FFND  2048
#define BH    (BATCH*NHEAD)   // 16

typedef float  f32x4  __attribute__((ext_vector_type(4)));
typedef __bf16 bf16x8 __attribute__((ext_vector_type(8)));

#define WAITVM(n) asm volatile("s_waitcnt vmcnt(" #n ")" ::: "memory")

// hardware RNE casts (v_cvt_pk_bf16_f32) — do NOT hand-roll bit ops (m240)
__device__ __forceinline__ unsigned short f2bf(float f) {
  union { __bf16 h; unsigned short u; } z; z.h = (__bf16)f; return z.u;
}
__device__ __forceinline__ float bf2f(unsigned short h) {
  union { unsigned u; float f; } x; x.u = ((unsigned)h) << 16;
  return x.f;
}
__device__ __forceinline__ unsigned pk2(float a, float b) {
  union { __bf16 h[2]; unsigned u; } z;
  z.h[0] = (__bf16)a; z.h[1] = (__bf16)b; return z.u;
}
__device__ __forceinline__ float gelu_f(float v) {
  float u = 0.7978845608f * (v + 0.044715f * v * v * v);
  float a = fabsf(u);
  float e = __expf(-2.f * a);
  float t = (1.f - e) / (1.f + e);
  t = copysignf(t, u);
  return 0.5f * v * (1.f + t);
}

__device__ __forceinline__ void load_lds16(const void* g, void* l) {
  __builtin_amdgcn_global_load_lds((const __attribute__((address_space(1))) void*)g,
                                   (__attribute__((address_space(3))) void*)l, 16, 0, 0);
}

// ---------------------------------------------------------------- prep ----
__global__ __launch_bounds__(256) void prep_misc(
    const float* __restrict__ x, const float* __restrict__ bq,
    const float* __restrict__ bk, const float* __restrict__ bv,
    unsigned short* __restrict__ xb, float* __restrict__ bqkv) {
  int gid = blockIdx.x * 256 + threadIdx.x;
  float4 v = ((const float4*)x)[gid];
  ushort4 s;
  s.x = f2bf(v.x); s.y = f2bf(v.y); s.z = f2bf(v.z); s.w = f2bf(v.w);
  ((ushort4*)xb)[gid] = s;
  if (gid < 1536)
    bqkv[gid] = gid < 512 ? bq[gid] : (gid < 1024 ? bk[gid - 512] : bv[gid - 1024]);
}

// all weight transposes fused: src f32 [R][C] -> dst bf16 [C][R]. block (32,8).
__global__ __launch_bounds__(256) void prep_weights(
    const float* __restrict__ Wq, const float* __restrict__ Wk,
    const float* __restrict__ Wv, const float* __restrict__ Wo,
    const float* __restrict__ F1, const float* __restrict__ F2,
    unsigned short* __restrict__ qkvT, unsigned short* __restrict__ WoT,
    unsigned short* __restrict__ F1T, unsigned short* __restrict__ F2T) {
  __shared__ float t[32][33];
  int bid = blockIdx.x;
  const float* src; unsigned short* dst; int R, C, tx, ty;
  if (bid < 1024) {
    int m = bid >> 8;
    src = m == 0 ? Wq : m == 1 ? Wk : m == 2 ? Wv : Wo;
    dst = m < 3 ? qkvT + m * 512 * 512 : WoT;
    R = 512; C = 512; int u = bid & 255; tx = u & 15; ty = u >> 4;
  } else if (bid < 2048) {
    src = F1; dst = F1T; R = 512; C = 2048;
    int u = bid - 1024; tx = u & 63; ty = u >> 6;
  } else {
    src = F2; dst = F2T; R = 2048; C = 512;
    int u = bid - 2048; tx = u & 15; ty = u >> 4;
  }
  int c0 = tx * 32, r0 = ty * 32;
  int x_ = threadIdx.x, y_ = threadIdx.y;
#pragma unroll
  for (int i = 0; i < 4; i++)
    t[y_ + i * 8][x_] = src[(size_t)(r0 + y_ + i * 8) * C + c0 + x_];
  __syncthreads();
#pragma unroll
  for (int i = 0; i < 4; i++)
    dst[(size_t)(c0 + y_ + i * 8) * R + r0 + x_] = f2bf(t[x_][y_ + i * 8]);
}

// ---------------------------------------------------------------- RPE -----
// rb1 folded into MFMA via K-element 4 (A row = rb1, B element = 1.0).
__global__ __launch_bounds__(256) void rpe_mfma(
    const float* __restrict__ rel, const float* __restrict__ R1,
    const float* __restrict__ rb1, const float* __restrict__ R2,
    const float* __restrict__ rb2, unsigned short* __restrict__ rpe) {
  __shared__ unsigned short Hs[4][64 * 64];
  __shared__ unsigned short Os[4][8 * 64];
  const int tid = threadIdx.x, lane = tid & 63, w = tid >> 6;
  const int l15 = lane & 15, l4g = lane >> 4;
  char* Hw = (char*)&Hs[w][0];
  char* Ow = (char*)&Os[w][0];

  bf16x8 a1[4];
#pragma unroll
  for (int mt = 0; mt < 4; mt++) {
    bf16x8 z = {};
    if (l4g == 0) {
      int m = mt * 16 + l15;
      z[0] = (__bf16)R1[0 * 64 + m];
      z[1] = (__bf16)R1[1 * 64 + m];
      z[2] = (__bf16)R1[2 * 64 + m];
      z[3] = (__bf16)R1[3 * 64 + m];
      z[4] = (__bf16)rb1[m];                 // bias row (k=4)
    }
    a1[mt] = z;
  }
  bf16x8 b2f[2];
#pragma unroll
  for (int ks = 0; ks < 2; ks++) {
    bf16x8 z = {};
    if (l15 < 8) {
#pragma unroll
      for (int j = 0; j < 8; j++)
        z[j] = (__bf16)R2[(ks * 32 + l4g * 8 + j) * 8 + l15];
    }
    b2f[ks] = z;
  }
  float rb2v = (l15 < 8) ? rb2[l15] : 0.f;

  const int nwaves = gridDim.x * 4;            // 4096
  const int wgid = blockIdx.x * 4 + w;
  for (int itr = 0; itr < 8; itr++) {
    int p0 = (wgid + itr * nwaves) * 64;
    bf16x8 b1[4];
#pragma unroll
    for (int nt = 0; nt < 4; nt++) {
      bf16x8 z = {};
      if (l4g == 0) {
        float4 rv = *(const float4*)&rel[(size_t)(p0 + nt * 16 + l15) * 4];
        z[0] = (__bf16)rv.x; z[1] = (__bf16)rv.y;
        z[2] = (__bf16)rv.z; z[3] = (__bf16)rv.w;
        z[4] = (__bf16)1.0f;                  // bias multiplier (k=4)
      }
      b1[nt] = z;
    }
#pragma unroll
    for (int nt = 0; nt < 4; nt++) {
#pragma unroll
      for (int mt = 0; mt < 4; mt++) {
        f32x4 hacc = __builtin_amdgcn_mfma_f32_16x16x32_bf16(
            a1[mt], b1[nt], (f32x4){0.f, 0.f, 0.f, 0.f}, 0, 0, 0);
        int row = nt * 16 + l15;
        int dim0 = mt * 16 + l4g * 4;
        float v0 = fmaxf(hacc[0], 0.f);
        float v1 = fmaxf(hacc[1], 0.f);
        float v2 = fmaxf(hacc[2], 0.f);
        float v3 = fmaxf(hacc[3], 0.f);
        int byte = (row * 128 + dim0 * 2) ^ ((row & 7) << 4);
        uint2 pk; pk.x = pk2(v0, v1); pk.y = pk2(v2, v3);
        *(uint2*)(Hw + byte) = pk;
      }
    }
    f32x4 acc2[4];
#pragma unroll
    for (int mt = 0; mt < 4; mt++) acc2[mt] = (f32x4){0.f, 0.f, 0.f, 0.f};
#pragma unroll
    for (int ks = 0; ks < 2; ks++) {
#pragma unroll
      for (int mt = 0; mt < 4; mt++) {
        int row = mt * 16 + l15;
        int byte = (row * 128 + (ks * 32 + l4g * 8) * 2) ^ ((l15 & 7) << 4);
        bf16x8 af = *(const bf16x8*)(Hw + byte);
        acc2[mt] = __builtin_amdgcn_mfma_f32_16x16x32_bf16(af, b2f[ks], acc2[mt], 0, 0, 0);
      }
    }
#pragma unroll
    for (int mt = 0; mt < 4; mt++) {
      if (l15 < 8) {
        int byte = (l15 * 128 + (mt * 16 + l4g * 4) * 2) ^ ((l15 & 7) << 4);
        uint2 pk;
        pk.x = pk2(acc2[mt][0] + rb2v, acc2[mt][1] + rb2v);
        pk.y = pk2(acc2[mt][2] + rb2v, acc2[mt][3] + rb2v);
        *(uint2*)(Ow + byte) = pk;
      }
    }
    {
      int h = lane >> 3, rb = (lane & 7) * 8;
      int byte = (h * 128 + rb * 2) ^ ((h & 7) << 4);
      uint4 ov = *(const uint4*)(Ow + byte);
      int b = p0 >> 20, ij0 = (p0 & 1048575) + rb;
      *(uint4*)&rpe[((size_t)(b * 8 + h) << 20) + ij0] = ov;
    }
  }
}

// ---------------------------------------------------------------- GEMM ----
// Counted-vmcnt 2-phase pipeline: stage(next); wait vmcnt(NL); raw barrier;
// compute(cur); raw barrier. Never drains prefetch mid-loop.
enum { EPI_F32 = 0, EPI_GELU = 1, EPI_QKV = 2 };

template <int EPI, int BMt, int BNt, int WM, int WN>
__global__ __launch_bounds__(256) void gemm_bt(
    const unsigned short* __restrict__ A, const unsigned short* __restrict__ Bt,
    const float* __restrict__ bias, void* __restrict__ O0, void* __restrict__ O1,
    void* __restrict__ O2, int M, int N, int K) {
  __shared__ unsigned short As[2][BMt * 64];
  __shared__ unsigned short Bs[2][BNt * 64];
  const int tid = threadIdx.x, lane = tid & 63, w = tid >> 6;
  const int wr = w >> 1, wc = w & 1;
  const int m0 = blockIdx.y * BMt, n0 = blockIdx.x * BNt;
  const int l15 = lane & 15, l4g = lane >> 4;
  constexpr int NL = BMt / 32 + BNt / 32;   // loads in flight per stage

  f32x4 acc[WM][WN];
#pragma unroll
  for (int i = 0; i < WM; i++)
#pragma unroll
    for (int j = 0; j < WN; j++) acc[i][j] = (f32x4){0.f, 0.f, 0.f, 0.f};

  auto stage = [&](int buf, int kt) {
#pragma unroll
    for (int it = 0; it < BMt / 32; ++it) {
      int c = it * 256 + tid, row = c >> 3;
      int s16 = (c & 7) ^ (row & 7);
      load_lds16(A + (size_t)(m0 + row) * K + kt * 64 + s16 * 8,
                 (char*)&As[buf][0] + c * 16);
    }
#pragma unroll
    for (int it = 0; it < BNt / 32; ++it) {
      int c = it * 256 + tid, row = c >> 3;
      int s16 = (c & 7) ^ (row & 7);
      load_lds16(Bt + (size_t)(n0 + row) * K + kt * 64 + s16 * 8,
                 (char*)&Bs[buf][0] + c * 16);
    }
  };

  const int nkt = K / 64;
  stage(0, 0);
  for (int kt = 0; kt < nkt; ++kt) {
    const int cur = kt & 1;
    if (kt + 1 < nkt) {
      stage(cur ^ 1, kt + 1);
      if constexpr (NL == 6) WAITVM(6); else WAITVM(4);
    } else {
      WAITVM(0);
    }
    __builtin_amdgcn_s_barrier();
#pragma unroll
    for (int kk = 0; kk < 2; ++kk) {
      bf16x8 af[WM], bfv[WN];
#pragma unroll
      for (int i = 0; i < WM; i++) {
        int row = wr * (WM * 16) + i * 16 + l15;
        af[i] = *(const bf16x8*)((char*)&As[cur][0] + row * 128 +
                                 (((kk * 4 + l4g) ^ (row & 7)) << 4));
      }
#pragma unroll
      for (int j = 0; j < WN; j++) {
        int row = wc * (WN * 16) + j * 16 + l15;
        bfv[j] = *(const bf16x8*)((char*)&Bs[cur][0] + row * 128 +
                                  (((kk * 4 + l4g) ^ (row & 7)) << 4));
      }
#pragma unroll
      for (int i = 0; i < WM; i++)
#pragma unroll
        for (int j = 0; j < WN; j++)
          acc[i][j] = __builtin_amdgcn_mfma_f32_16x16x32_bf16(af[i], bfv[j], acc[i][j], 0, 0, 0);
    }
    if (kt + 1 < nkt) {
      asm volatile("" ::: "memory");
      __builtin_amdgcn_s_barrier();   // protect cur before kt+1 overwrites it
    }
  }

#pragma unroll
  for (int i = 0; i < WM; i++) {
    int row = m0 + wr * (WM * 16) + i * 16 + l4g * 4;
#pragma unroll
    for (int j = 0; j < WN; j++) {
      int col = n0 + wc * (WN * 16) + j * 16 + l15;
      float bv = bias ? bias[col] : 0.f;
#pragma unroll
      for (int r = 0; r < 4; r++) {
        float v = acc[i][j][r] + bv;
        int rr = row + r;
        if (EPI == EPI_F32) {
          ((float*)O0)[(size_t)rr * N + col] = v;
        } else if (EPI == EPI_GELU) {
          ((unsigned short*)O0)[(size_t)rr * N + col] = f2bf(gelu_f(v));
        } else {  // QKV scatter
          int b = rr >> 10, n = rr & 1023;
          int d = col & 511, h = d >> 6, hd = d & 63;
          int bh = b * 8 + h;
          unsigned short bv16 = f2bf(v);
          if (col < 512)
            ((unsigned short*)O0)[((size_t)bh * 1024 + n) * 64 + hd] = bv16;
          else if (col < 1024)
            ((unsigned short*)O1)[((size_t)bh * 1024 + n) * 64 + hd] = bv16;
          else
            ((unsigned short*)O2)[((size_t)bh * 64 + hd) * 1024 + n] = bv16;
        }
      }
    }
  }
}

// ------------------------------------------------------------- attention --
__global__ __launch_bounds__(256) void attn_kernel(
    const unsigned short* __restrict__ Qh, const unsigned short* __restrict__ Kh,
    const unsigned short* __restrict__ VT, const unsigned short* __restrict__ rpe,
    unsigned short* __restrict__ AO) {
  __shared__ unsigned short Ks[2][64 * 64], Vs[2][64 * 64], Rs[2][64 * 64];
  __shared__ unsigned short Ps[4][16 * 64];
  const int tid = threadIdx.x, lane = tid & 63, w = tid >> 6;
  const int l15 = lane & 15, l4g = lane >> 4;
  const int bid = blockIdx.x;
  const int it = (bid >> 3) & 15;
  const int bh = (bid & 7) | ((bid >> 7) << 3);
  const int i0 = it * 64;
  const unsigned short* Qb = Qh + (size_t)bh * SEQ * HDIM;
  const unsigned short* Kb = Kh + (size_t)bh * SEQ * HDIM;
  const unsigned short* Vb = VT + (size_t)bh * HDIM * SEQ;
  const unsigned short* Rb = rpe + ((size_t)bh << 20);

  bf16x8 qf[2];
#pragma unroll
  for (int kk = 0; kk < 2; kk++)
    qf[kk] = *(const bf16x8*)&Qb[(size_t)(i0 + w * 16 + l15) * 64 + kk * 32 + l4g * 8];

  f32x4 o[4];
#pragma unroll
  for (int i = 0; i < 4; i++) o[i] = (f32x4){0.f, 0.f, 0.f, 0.f};
  float m4[4], l4s[4];
#pragma unroll
  for (int r = 0; r < 4; r++) { m4[r] = -1e30f; l4s[r] = 0.f; }

  auto stage = [&](int buf, int jt) {
    int j0 = jt * 64;
#pragma unroll
    for (int itn = 0; itn < 2; ++itn) {
      int c = itn * 256 + tid, row = c >> 3;
      int s8 = ((c & 7) ^ (row & 7)) * 8;
      load_lds16(Kb + (size_t)(j0 + row) * 64 + s8, (char*)&Ks[buf][0] + c * 16);
      load_lds16(Vb + (size_t)row * SEQ + j0 + s8, (char*)&Vs[buf][0] + c * 16);
      load_lds16(Rb + (size_t)(i0 + row) * SEQ + j0 + s8, (char*)&Rs[buf][0] + c * 16);
    }
  };

  stage(0, 0);
  for (int jt = 0; jt < 16; ++jt) {
    const int cur = jt & 1;
    if (jt < 15) {
      stage(cur ^ 1, jt + 1);
      WAITVM(6);
    } else {
      WAITVM(0);
    }
    __builtin_amdgcn_s_barrier();

    f32x4 sa[4];
#pragma unroll
    for (int js = 0; js < 4; js++) sa[js] = (f32x4){0.f, 0.f, 0.f, 0.f};
#pragma unroll
    for (int kk = 0; kk < 2; kk++) {
#pragma unroll
      for (int js = 0; js < 4; js++) {
        int row = js * 16 + l15;
        bf16x8 kb = *(const bf16x8*)((char*)&Ks[cur][0] + row * 128 +
                                     (((kk * 4 + l4g) ^ (row & 7)) << 4));
        sa[js] = __builtin_amdgcn_mfma_f32_16x16x32_bf16(qf[kk], kb, sa[js], 0, 0, 0);
      }
    }
    float p[4][4], mx[4];
#pragma unroll
    for (int r = 0; r < 4; r++) mx[r] = -1e30f;
#pragma unroll
    for (int js = 0; js < 4; js++)
#pragma unroll
      for (int r = 0; r < 4; r++) {
        int row = w * 16 + l4g * 4 + r;
        int byte = row * 128 + ((((js * 2) + (l15 >> 3)) ^ (row & 7)) << 4) + ((l15 & 7) << 1);
        float rv = bf2f(*(const unsigned short*)((const char*)&Rs[cur][0] + byte));
        float s = sa[js][r] * 0.125f + rv;
        p[js][r] = s;
        mx[r] = fmaxf(mx[r], s);
      }
#pragma unroll
    for (int off = 1; off < 16; off <<= 1)
#pragma unroll
      for (int r = 0; r < 4; r++) mx[r] = fmaxf(mx[r], __shfl_xor(mx[r], off));
    float al[4], sm[4];
#pragma unroll
    for (int r = 0; r < 4; r++) {
      float nm = fmaxf(m4[r], mx[r]);
      al[r] = __expf(m4[r] - nm);
      m4[r] = nm;
      sm[r] = 0.f;
    }
#pragma unroll
    for (int js = 0; js < 4; js++)
#pragma unroll
      for (int r = 0; r < 4; r++) {
        float e = __expf(p[js][r] - m4[r]);
        p[js][r] = e;
        sm[r] += e;
      }
#pragma unroll
    for (int off = 1; off < 16; off <<= 1)
#pragma unroll
      for (int r = 0; r < 4; r++) sm[r] += __shfl_xor(sm[r], off);
#pragma unroll
    for (int r = 0; r < 4; r++) l4s[r] = l4s[r] * al[r] + sm[r];
#pragma unroll
    for (int hdf = 0; hdf < 4; hdf++)
#pragma unroll
      for (int r = 0; r < 4; r++) o[hdf][r] *= al[r];
#pragma unroll
    for (int js = 0; js < 4; js++)
#pragma unroll
      for (int r = 0; r < 4; r++) {
        int row = l4g * 4 + r;
        int byte = row * 128 + ((((js * 2) + (l15 >> 3)) ^ (row & 7)) << 4) + ((l15 & 7) << 1);
        *(unsigned short*)((char*)&Ps[w][0] + byte) = f2bf(p[js][r]);
      }
#pragma unroll
    for (int kk = 0; kk < 2; kk++) {
      bf16x8 pf = *(const bf16x8*)((char*)&Ps[w][0] + l15 * 128 +
                                   (((kk * 4 + l4g) ^ (l15 & 7)) << 4));
#pragma unroll
      for (int hdf = 0; hdf < 4; hdf++) {
        int row = hdf * 16 + l15;
        bf16x8 vb = *(const bf16x8*)((char*)&Vs[cur][0] + row * 128 +
                                     (((kk * 4 + l4g) ^ (row & 7)) << 4));
        o[hdf] = __builtin_amdgcn_mfma_f32_16x16x32_bf16(pf, vb, o[hdf], 0, 0, 0);
      }
    }
    if (jt < 15) {
      asm volatile("" ::: "memory");
      __builtin_amdgcn_s_barrier();
    }
  }
  const int b = bh >> 3, h = bh & 7;
#pragma unroll
  for (int hdf = 0; hdf < 4; hdf++)
#pragma unroll
    for (int r = 0; r < 4; r++) {
      float v = o[hdf][r] / l4s[r];
      int n = i0 + w * 16 + l4g * 4 + r;
      AO[((size_t)b * SEQ + n) * DMODEL + h * 64 + hdf * 16 + l15] = f2bf(v);
    }
}

// ---------------------------------------------------------------- LN ------
__global__ __launch_bounds__(256) void ln_kernel(
    const float* __restrict__ a, const float* __restrict__ res,
    const float* __restrict__ g, const float* __restrict__ be,
    float* __restrict__ outf, unsigned short* __restrict__ outb) {
  const int row = blockIdx.x, t = threadIdx.x;
  const float* pa = a + (size_t)row * DMODEL;
  const float* pb = res + (size_t)row * DMODEL;
  float v0 = pa[t] + pb[t];
  float v1 = pa[t + 256] + pb[t + 256];
  float s = v0 + v1, sq = v0 * v0 + v1 * v1;
#pragma unroll
  for (int off = 1; off < 64; off <<= 1) {
    s += __shfl_xor(s, off);
    sq += __shfl_xor(sq, off);
  }
  __shared__ float ls[4], lq[4];
  int w = t >> 6, lane = t & 63;
  if (lane == 0) { ls[w] = s; lq[w] = sq; }
  __syncthreads();
  s = ls[0] + ls[1] + ls[2] + ls[3];
  sq = lq[0] + lq[1] + lq[2] + lq[3];
  float mu = s * (1.f / DMODEL);
  float var = sq * (1.f / DMODEL) - mu * mu;
  float rs = rsqrtf(var + 1e-5f);
  float y0 = (v0 - mu) * rs * g[t] + be[t];
  float y1v = (v1 - mu) * rs * g[t + 256] + be[t + 256];
  outf[(size_t)row * DMODEL + t] = y0;
  outf[(size_t)row * DMODEL + t + 256] = y1v;
  if (outb) {
    outb[(size_t)row * DMODEL + t] = f2bf(y0);
    outb[(size_t)row * DMODEL + t + 256] = f2bf(y1v);
  }
}

// ---------------------------------------------------------------- launch --
extern "C" void kernel_launch(void* const* d_in, const int* in_sizes, int n_in,
                              void* d_out, int out_size, void* d_ws, size_t ws_size,
                              hipStream_t stream) {
  const float* x   = (const float*)d_in[0];
  const float* rel = (const float*)d_in[1];
  const float* Wq  = (const float*)d_in[2];
  const float* bq  = (const float*)d_in[3];
  const float* Wk  = (const float*)d_in[4];
  const float* bk  = (const float*)d_in[5];
  const float* Wv  = (const float*)d_in[6];
  const float* bv  = (const float*)d_in[7];
  const float* Wo  = (const float*)d_in[8];
  const float* bo  = (const float*)d_in[9];
  const float* R1  = (const float*)d_in[10];
  const float* rb1 = (const float*)d_in[11];
  const float* R2  = (const float*)d_in[12];
  const float* rb2 = (const float*)d_in[13];
  const float* g1  = (const float*)d_in[14];
  const float* b1  = (const float*)d_in[15];
  const float* g2  = (const float*)d_in[16];
  const float* b2  = (const float*)d_in[17];
  const float* F1  = (const float*)d_in[18];
  const float* fb1 = (const float*)d_in[19];
  const float* F2  = (const float*)d_in[20];
  const float* fb2 = (const float*)d_in[21];

  char* p = (char*)d_ws;
  auto alloc = [&](size_t bytes) {
    char* r = p;
    p += (bytes + 255) & ~(size_t)255;
    return r;
  };
  unsigned short* xb   = (unsigned short*)alloc((size_t)2048 * 512 * 2);
  unsigned short* qkvT = (unsigned short*)alloc((size_t)1536 * 512 * 2);
  float*          bqkv = (float*)alloc(1536 * 4);
  unsigned short* WoT  = (unsigned short*)alloc((size_t)512 * 512 * 2);
  unsigned short* F1T  = (unsigned short*)alloc((size_t)2048 * 512 * 2);
  unsigned short* F2T  = (unsigned short*)alloc((size_t)512 * 2048 * 2);
  unsigned short* Qhp  = (unsigned short*)alloc((size_t)BH * SEQ * HDIM * 2);
  unsigned short* Khp  = (unsigned short*)alloc((size_t)BH * SEQ * HDIM * 2);
  unsigned short* VTp  = (unsigned short*)alloc((size_t)BH * HDIM * SEQ * 2);
  unsigned short* rpep = (unsigned short*)alloc((size_t)BH * SEQ * SEQ * 2);   // 32MB
  unsigned short* attO = (unsigned short*)alloc((size_t)2048 * 512 * 2);
  float*          t1   = (float*)alloc((size_t)2048 * 512 * 4);
  float*          y1   = (float*)alloc((size_t)2048 * 512 * 4);
  unsigned short* y1b  = (unsigned short*)alloc((size_t)2048 * 512 * 2);
  float*          t2   = t1;                     // t1 dead after LN1
  unsigned short* hbuf = rpep;                   // rpe dead after attention

  prep_misc<<<1024, 256, 0, stream>>>(x, bq, bk, bv, xb, bqkv);
  prep_weights<<<3072, dim3(32, 8), 0, stream>>>(Wq, Wk, Wv, Wo, F1, F2,
                                                 qkvT, WoT, F1T, F2T);
  rpe_mfma<<<1024, 256, 0, stream>>>(rel, R1, rb1, R2, rb2, rpep);

  // QKV: 128x64 tiles -> 384 blocks
  gemm_bt<EPI_QKV, 128, 64, 4, 2><<<dim3(24, 16), 256, 0, stream>>>(
      xb, qkvT, bqkv, Qhp, Khp, VTp, 2048, 1536, 512);
  attn_kernel<<<256, 256, 0, stream>>>(Qhp, Khp, VTp, rpep, attO);

  // Wo: 64x64 tiles -> 256 blocks
  gemm_bt<EPI_F32, 64, 64, 2, 2><<<dim3(8, 32), 256, 0, stream>>>(
      attO, WoT, bo, t1, nullptr, nullptr, 2048, 512, 512);
  ln_kernel<<<2048, 256, 0, stream>>>(x, t1, g1, b1, y1, y1b);

  // FFN1: 128x64 tiles -> 512 blocks
  gemm_bt<EPI_GELU, 128, 64, 4, 2><<<dim3(32, 16), 256, 0, stream>>>(
      y1b, F1T, fb1, hbuf, nullptr, nullptr, 2048, 2048, 512);
  // FFN2: 64x64 tiles -> 256 blocks
  gemm_bt<EPI_F32, 64, 64, 2, 2><<<dim3(8, 32), 256, 0, stream>>>(
      hbuf, F2T, fb2, t2, nullptr, nullptr, 2048, 512, 2048);
  ln_kernel<<<2048, 256, 0, stream>>>(y1, t2, g2, b2, (float*)d_out, nullptr);
}

// Round 6
// 245.435 us; speedup vs baseline: 1.3214x; 1.0241x over previous
//
#include <hip/hip_runtime.h>
#include <math.h>

// Problem constants
#define BATCH 2
#define SEQ   1024
#define DMODEL 512
#define NHEAD 8
#define HDIM  64
#define FFND  2048
#define BH    (BATCH*NHEAD)   // 16

typedef float  f32x4   __attribute__((ext_vector_type(4)));
typedef float  f32x16  __attribute__((ext_vector_type(16)));
typedef __bf16 bf16x8  __attribute__((ext_vector_type(8)));

#define WAITVM(n) asm volatile("s_waitcnt vmcnt(" #n ")" ::: "memory")

// hardware RNE casts (v_cvt_pk_bf16_f32)
__device__ __forceinline__ unsigned short f2bf(float f) {
  union { __bf16 h; unsigned short u; } z; z.h = (__bf16)f; return z.u;
}
__device__ __forceinline__ float bf2f(unsigned short h) {
  union { unsigned u; float f; } x; x.u = ((unsigned)h) << 16;
  return x.f;
}
__device__ __forceinline__ unsigned pk2(float a, float b) {
  union { __bf16 h[2]; unsigned u; } z;
  z.h[0] = (__bf16)a; z.h[1] = (__bf16)b; return z.u;
}
__device__ __forceinline__ float gelu_f(float v) {
  float u = 0.7978845608f * (v + 0.044715f * v * v * v);
  float a = fabsf(u);
  float e = __expf(-2.f * a);
  float t = (1.f - e) / (1.f + e);
  t = copysignf(t, u);
  return 0.5f * v * (1.f + t);
}

__device__ __forceinline__ void load_lds16(const void* g, void* l) {
  __builtin_amdgcn_global_load_lds((const __attribute__((address_space(1))) void*)g,
                                   (__attribute__((address_space(3))) void*)l, 16, 0, 0);
}

// ---------------------------------------------------------------- prep ----
__global__ __launch_bounds__(256) void prep_misc(
    const float* __restrict__ x, const float* __restrict__ bq,
    const float* __restrict__ bk, const float* __restrict__ bv,
    unsigned short* __restrict__ xb, float* __restrict__ bqkv) {
  int gid = blockIdx.x * 256 + threadIdx.x;
  float4 v = ((const float4*)x)[gid];
  ushort4 s;
  s.x = f2bf(v.x); s.y = f2bf(v.y); s.z = f2bf(v.z); s.w = f2bf(v.w);
  ((ushort4*)xb)[gid] = s;
  if (gid < 1536)
    bqkv[gid] = gid < 512 ? bq[gid] : (gid < 1024 ? bk[gid - 512] : bv[gid - 1024]);
}

// all weight transposes fused: src f32 [R][C] -> dst bf16 [C][R]. block (32,8).
__global__ __launch_bounds__(256) void prep_weights(
    const float* __restrict__ Wq, const float* __restrict__ Wk,
    const float* __restrict__ Wv, const float* __restrict__ Wo,
    const float* __restrict__ F1, const float* __restrict__ F2,
    unsigned short* __restrict__ qkvT, unsigned short* __restrict__ WoT,
    unsigned short* __restrict__ F1T, unsigned short* __restrict__ F2T) {
  __shared__ float t[32][33];
  int bid = blockIdx.x;
  const float* src; unsigned short* dst; int R, C, tx, ty;
  if (bid < 1024) {
    int m = bid >> 8;
    src = m == 0 ? Wq : m == 1 ? Wk : m == 2 ? Wv : Wo;
    dst = m < 3 ? qkvT + m * 512 * 512 : WoT;
    R = 512; C = 512; int u = bid & 255; tx = u & 15; ty = u >> 4;
  } else if (bid < 2048) {
    src = F1; dst = F1T; R = 512; C = 2048;
    int u = bid - 1024; tx = u & 63; ty = u >> 6;
  } else {
    src = F2; dst = F2T; R = 2048; C = 512;
    int u = bid - 2048; tx = u & 15; ty = u >> 4;
  }
  int c0 = tx * 32, r0 = ty * 32;
  int x_ = threadIdx.x, y_ = threadIdx.y;
#pragma unroll
  for (int i = 0; i < 4; i++)
    t[y_ + i * 8][x_] = src[(size_t)(r0 + y_ + i * 8) * C + c0 + x_];
  __syncthreads();
#pragma unroll
  for (int i = 0; i < 4; i++)
    dst[(size_t)(c0 + y_ + i * 8) * R + r0 + x_] = f2bf(t[x_][y_ + i * 8]);
}

// ---------------------------------------------------------------- RPE -----
// v3: GEMM1 via mfma_32x32x16 (K=4+bias in K=16), 32-row chunks,
// hidden through wave-private swizzled LDS, GEMM2 via 16x16x32.
__global__ __launch_bounds__(256) void rpe_mfma(
    const float* __restrict__ rel, const float* __restrict__ R1,
    const float* __restrict__ rb1, const float* __restrict__ R2,
    const float* __restrict__ rb2, unsigned short* __restrict__ rpe) {
  __shared__ unsigned short Hs[4][32 * 64];   // 4KB per wave
  __shared__ unsigned short Os[4][8 * 32];    // 512B per wave
  const int tid = threadIdx.x, lane = tid & 63, w = tid >> 6;
  const int l31 = lane & 31, hi = lane >> 5;
  const int l15 = lane & 15, l4g = lane >> 4;
  char* Hw = (char*)&Hs[w][0];
  char* Ow = (char*)&Os[w][0];

  // GEMM1 A-frags (32x32x16): lane holds A[d = mt*32+l31][k = hi*8+j]
  // A[d][k] = R1[k][d] (k<4), rb1[d] (k==4), else 0.
  bf16x8 a1[2];
#pragma unroll
  for (int mt = 0; mt < 2; mt++) {
    bf16x8 z = {};
    if (hi == 0) {
      int d = mt * 32 + l31;
      z[0] = (__bf16)R1[0 * 64 + d];
      z[1] = (__bf16)R1[1 * 64 + d];
      z[2] = (__bf16)R1[2 * 64 + d];
      z[3] = (__bf16)R1[3 * 64 + d];
      z[4] = (__bf16)rb1[d];
    }
    a1[mt] = z;
  }
  // GEMM2 B-frag (16x16x32): lane holds R2[k=ks*32+l4g*8+j][h=l15], h<8
  bf16x8 b2f[2];
#pragma unroll
  for (int ks = 0; ks < 2; ks++) {
    bf16x8 z = {};
    if (l15 < 8) {
#pragma unroll
      for (int j = 0; j < 8; j++)
        z[j] = (__bf16)R2[(ks * 32 + l4g * 8 + j) * 8 + l15];
    }
    b2f[ks] = z;
  }
  float rb2v = (l15 < 8) ? rb2[l15] : 0.f;

  const int wgid = blockIdx.x * 4 + w;          // 8192 waves
  for (int c = 0; c < 8; c++) {
    int p0 = (wgid + c * 8192) * 32;            // 32-row chunk base
    // GEMM1 B-frag: B[k][r] = rel[p0+r][k] (k<4), 1.0 (k==4)
    bf16x8 b1 = {};
    if (hi == 0) {
      float4 rv = *(const float4*)&rel[(size_t)(p0 + l31) * 4];
      b1[0] = (__bf16)rv.x; b1[1] = (__bf16)rv.y;
      b1[2] = (__bf16)rv.z; b1[3] = (__bf16)rv.w;
      b1[4] = (__bf16)1.0f;
    }
    // GEMM1 + ReLU + pack to LDS (rows r=l31, dims mt*32+8q+4hi+0..3)
#pragma unroll
    for (int mt = 0; mt < 2; mt++) {
      f32x16 hz = {};
      f32x16 h = __builtin_amdgcn_mfma_f32_32x32x16_bf16(a1[mt], b1, hz, 0, 0, 0);
#pragma unroll
      for (int q = 0; q < 4; q++) {
        float v0 = fmaxf(h[4 * q + 0], 0.f), v1 = fmaxf(h[4 * q + 1], 0.f);
        float v2 = fmaxf(h[4 * q + 2], 0.f), v3 = fmaxf(h[4 * q + 3], 0.f);
        uint2 pk; pk.x = pk2(v0, v1); pk.y = pk2(v2, v3);
        int byte = (l31 * 128 + (mt * 32 + q * 8 + hi * 4) * 2) ^ ((l31 & 7) << 4);
        *(uint2*)(Hw + byte) = pk;
      }
    }
    // GEMM2: out[r][h] over K=64 dims
    f32x4 acc2[2];
    acc2[0] = (f32x4){0.f, 0.f, 0.f, 0.f};
    acc2[1] = (f32x4){0.f, 0.f, 0.f, 0.f};
#pragma unroll
    for (int ks = 0; ks < 2; ks++)
#pragma unroll
      for (int mt2 = 0; mt2 < 2; mt2++) {
        int row = mt2 * 16 + l15;
        int byte = (row * 128 + (ks * 32 + l4g * 8) * 2) ^ ((row & 7) << 4);
        bf16x8 af = *(const bf16x8*)(Hw + byte);
        acc2[mt2] = __builtin_amdgcn_mfma_f32_16x16x32_bf16(af, b2f[ks], acc2[mt2], 0, 0, 0);
      }
    // D: col=l15=h, row = mt2*16 + l4g*4 + reg -> Os[h][row] packed pairs
#pragma unroll
    for (int mt2 = 0; mt2 < 2; mt2++) {
      if (l15 < 8) {
        uint2 pk;
        pk.x = pk2(acc2[mt2][0] + rb2v, acc2[mt2][1] + rb2v);
        pk.y = pk2(acc2[mt2][2] + rb2v, acc2[mt2][3] + rb2v);
        int byte = l15 * 64 + (mt2 * 16 + l4g * 4) * 2;
        *(uint2*)(Ow + byte) = pk;
      }
    }
    // coalesced store: lane -> h=lane>>3, rows j0=(lane&7)*4 .. +3 (8B)
    {
      int h = lane >> 3, j0 = (lane & 7) * 4;
      uint2 ov = *(const uint2*)(Ow + h * 64 + j0 * 2);
      int b = p0 >> 20, ij0 = (p0 & 1048575) + j0;
      *(uint2*)&rpe[((size_t)(b * 8 + h) << 20) + ij0] = ov;
    }
  }
}

// ---------------------------------------------------------------- GEMM ----
// Counted-vmcnt 2-phase pipeline.
enum { EPI_F32 = 0, EPI_GELU = 1, EPI_QKV = 2 };

template <int EPI, int BMt, int BNt, int WM, int WN>
__global__ __launch_bounds__(256) void gemm_bt(
    const unsigned short* __restrict__ A, const unsigned short* __restrict__ Bt,
    const float* __restrict__ bias, void* __restrict__ O0, void* __restrict__ O1,
    void* __restrict__ O2, int M, int N, int K) {
  __shared__ unsigned short As[2][BMt * 64];
  __shared__ unsigned short Bs[2][BNt * 64];
  const int tid = threadIdx.x, lane = tid & 63, w = tid >> 6;
  const int wr = w >> 1, wc = w & 1;
  const int m0 = blockIdx.y * BMt, n0 = blockIdx.x * BNt;
  const int l15 = lane & 15, l4g = lane >> 4;
  constexpr int NL = BMt / 32 + BNt / 32;

  f32x4 acc[WM][WN];
#pragma unroll
  for (int i = 0; i < WM; i++)
#pragma unroll
    for (int j = 0; j < WN; j++) acc[i][j] = (f32x4){0.f, 0.f, 0.f, 0.f};

  auto stage = [&](int buf, int kt) {
#pragma unroll
    for (int it = 0; it < BMt / 32; ++it) {
      int c = it * 256 + tid, row = c >> 3;
      int s16 = (c & 7) ^ (row & 7);
      load_lds16(A + (size_t)(m0 + row) * K + kt * 64 + s16 * 8,
                 (char*)&As[buf][0] + c * 16);
    }
#pragma unroll
    for (int it = 0; it < BNt / 32; ++it) {
      int c = it * 256 + tid, row = c >> 3;
      int s16 = (c & 7) ^ (row & 7);
      load_lds16(Bt + (size_t)(n0 + row) * K + kt * 64 + s16 * 8,
                 (char*)&Bs[buf][0] + c * 16);
    }
  };

  const int nkt = K / 64;
  stage(0, 0);
  for (int kt = 0; kt < nkt; ++kt) {
    const int cur = kt & 1;
    if (kt + 1 < nkt) {
      stage(cur ^ 1, kt + 1);
      if constexpr (NL == 6) WAITVM(6); else WAITVM(4);
    } else {
      WAITVM(0);
    }
    __builtin_amdgcn_s_barrier();
#pragma unroll
    for (int kk = 0; kk < 2; ++kk) {
      bf16x8 af[WM], bfv[WN];
#pragma unroll
      for (int i = 0; i < WM; i++) {
        int row = wr * (WM * 16) + i * 16 + l15;
        af[i] = *(const bf16x8*)((char*)&As[cur][0] + row * 128 +
                                 (((kk * 4 + l4g) ^ (row & 7)) << 4));
      }
#pragma unroll
      for (int j = 0; j < WN; j++) {
        int row = wc * (WN * 16) + j * 16 + l15;
        bfv[j] = *(const bf16x8*)((char*)&Bs[cur][0] + row * 128 +
                                  (((kk * 4 + l4g) ^ (row & 7)) << 4));
      }
#pragma unroll
      for (int i = 0; i < WM; i++)
#pragma unroll
        for (int j = 0; j < WN; j++)
          acc[i][j] = __builtin_amdgcn_mfma_f32_16x16x32_bf16(af[i], bfv[j], acc[i][j], 0, 0, 0);
    }
    if (kt + 1 < nkt) {
      asm volatile("" ::: "memory");
      __builtin_amdgcn_s_barrier();
    }
  }

#pragma unroll
  for (int i = 0; i < WM; i++) {
    int row = m0 + wr * (WM * 16) + i * 16 + l4g * 4;
#pragma unroll
    for (int j = 0; j < WN; j++) {
      int col = n0 + wc * (WN * 16) + j * 16 + l15;
      float bv = bias ? bias[col] : 0.f;
#pragma unroll
      for (int r = 0; r < 4; r++) {
        float v = acc[i][j][r] + bv;
        int rr = row + r;
        if (EPI == EPI_F32) {
          ((float*)O0)[(size_t)rr * N + col] = v;
        } else if (EPI == EPI_GELU) {
          ((unsigned short*)O0)[(size_t)rr * N + col] = f2bf(gelu_f(v));
        } else {  // QKV scatter
          int b = rr >> 10, n = rr & 1023;
          int d = col & 511, h = d >> 6, hd = d & 63;
          int bh = b * 8 + h;
          unsigned short bv16 = f2bf(v);
          if (col < 512)
            ((unsigned short*)O0)[((size_t)bh * 1024 + n) * 64 + hd] = bv16;
          else if (col < 1024)
            ((unsigned short*)O1)[((size_t)bh * 1024 + n) * 64 + hd] = bv16;
          else
            ((unsigned short*)O2)[((size_t)bh * 64 + hd) * 1024 + n] = bv16;
        }
      }
    }
  }
}

// ------------------------------------------------------------- attention --
__global__ __launch_bounds__(256) void attn_kernel(
    const unsigned short* __restrict__ Qh, const unsigned short* __restrict__ Kh,
    const unsigned short* __restrict__ VT, const unsigned short* __restrict__ rpe,
    unsigned short* __restrict__ AO) {
  __shared__ unsigned short Ks[2][64 * 64], Vs[2][64 * 64], Rs[2][64 * 64];
  __shared__ unsigned short Ps[4][16 * 64];
  const int tid = threadIdx.x, lane = tid & 63, w = tid >> 6;
  const int l15 = lane & 15, l4g = lane >> 4;
  const int bid = blockIdx.x;
  const int it = (bid >> 3) & 15;
  const int bh = (bid & 7) | ((bid >> 7) << 3);
  const int i0 = it * 64;
  const unsigned short* Qb = Qh + (size_t)bh * SEQ * HDIM;
  const unsigned short* Kb = Kh + (size_t)bh * SEQ * HDIM;
  const unsigned short* Vb = VT + (size_t)bh * HDIM * SEQ;
  const unsigned short* Rb = rpe + ((size_t)bh << 20);

  bf16x8 qf[2];
#pragma unroll
  for (int kk = 0; kk < 2; kk++)
    qf[kk] = *(const bf16x8*)&Qb[(size_t)(i0 + w * 16 + l15) * 64 + kk * 32 + l4g * 8];

  f32x4 o[4];
#pragma unroll
  for (int i = 0; i < 4; i++) o[i] = (f32x4){0.f, 0.f, 0.f, 0.f};
  float m4[4], l4s[4];
#pragma unroll
  for (int r = 0; r < 4; r++) { m4[r] = -1e30f; l4s[r] = 0.f; }

  auto stage = [&](int buf, int jt) {
    int j0 = jt * 64;
#pragma unroll
    for (int itn = 0; itn < 2; ++itn) {
      int c = itn * 256 + tid, row = c >> 3;
      int s8 = ((c & 7) ^ (row & 7)) * 8;
      load_lds16(Kb + (size_t)(j0 + row) * 64 + s8, (char*)&Ks[buf][0] + c * 16);
      load_lds16(Vb + (size_t)row * SEQ + j0 + s8, (char*)&Vs[buf][0] + c * 16);
      load_lds16(Rb + (size_t)(i0 + row) * SEQ + j0 + s8, (char*)&Rs[buf][0] + c * 16);
    }
  };

  stage(0, 0);
  for (int jt = 0; jt < 16; ++jt) {
    const int cur = jt & 1;
    if (jt < 15) {
      stage(cur ^ 1, jt + 1);
      WAITVM(6);
    } else {
      WAITVM(0);
    }
    __builtin_amdgcn_s_barrier();

    f32x4 sa[4];
#pragma unroll
    for (int js = 0; js < 4; js++) sa[js] = (f32x4){0.f, 0.f, 0.f, 0.f};
    __builtin_amdgcn_s_setprio(1);
#pragma unroll
    for (int kk = 0; kk < 2; kk++) {
#pragma unroll
      for (int js = 0; js < 4; js++) {
        int row = js * 16 + l15;
        bf16x8 kb = *(const bf16x8*)((char*)&Ks[cur][0] + row * 128 +
                                     (((kk * 4 + l4g) ^ (row & 7)) << 4));
        sa[js] = __builtin_amdgcn_mfma_f32_16x16x32_bf16(qf[kk], kb, sa[js], 0, 0, 0);
      }
    }
    __builtin_amdgcn_s_setprio(0);
    float p[4][4], mx[4];
#pragma unroll
    for (int r = 0; r < 4; r++) mx[r] = -1e30f;
#pragma unroll
    for (int js = 0; js < 4; js++)
#pragma unroll
      for (int r = 0; r < 4; r++) {
        int row = w * 16 + l4g * 4 + r;
        int byte = row * 128 + ((((js * 2) + (l15 >> 3)) ^ (row & 7)) << 4) + ((l15 & 7) << 1);
        float rv = bf2f(*(const unsigned short*)((const char*)&Rs[cur][0] + byte));
        float s = sa[js][r] * 0.125f + rv;
        p[js][r] = s;
        mx[r] = fmaxf(mx[r], s);
      }
#pragma unroll
    for (int off = 1; off < 16; off <<= 1)
#pragma unroll
      for (int r = 0; r < 4; r++) mx[r] = fmaxf(mx[r], __shfl_xor(mx[r], off));
    float al[4], sm[4];
#pragma unroll
    for (int r = 0; r < 4; r++) {
      float nm = fmaxf(m4[r], mx[r]);
      al[r] = __expf(m4[r] - nm);
      m4[r] = nm;
      sm[r] = 0.f;
    }
#pragma unroll
    for (int js = 0; js < 4; js++)
#pragma unroll
      for (int r = 0; r < 4; r++) {
        float e = __expf(p[js][r] - m4[r]);
        p[js][r] = e;
        sm[r] += e;
      }
#pragma unroll
    for (int off = 1; off < 16; off <<= 1)
#pragma unroll
      for (int r = 0; r < 4; r++) sm[r] += __shfl_xor(sm[r], off);
#pragma unroll
    for (int r = 0; r < 4; r++) l4s[r] = l4s[r] * al[r] + sm[r];
#pragma unroll
    for (int hdf = 0; hdf < 4; hdf++)
#pragma unroll
      for (int r = 0; r < 4; r++) o[hdf][r] *= al[r];
#pragma unroll
    for (int js = 0; js < 4; js++)
#pragma unroll
      for (int r = 0; r < 4; r++) {
        int row = l4g * 4 + r;
        int byte = row * 128 + ((((js * 2) + (l15 >> 3)) ^ (row & 7)) << 4) + ((l15 & 7) << 1);
        *(unsigned short*)((char*)&Ps[w][0] + byte) = f2bf(p[js][r]);
      }
    __builtin_amdgcn_s_setprio(1);
#pragma unroll
    for (int kk = 0; kk < 2; kk++) {
      bf16x8 pf = *(const bf16x8*)((char*)&Ps[w][0] + l15 * 128 +
                                   (((kk * 4 + l4g) ^ (l15 & 7)) << 4));
#pragma unroll
      for (int hdf = 0; hdf < 4; hdf++) {
        int row = hdf * 16 + l15;
        bf16x8 vb = *(const bf16x8*)((char*)&Vs[cur][0] + row * 128 +
                                     (((kk * 4 + l4g) ^ (row & 7)) << 4));
        o[hdf] = __builtin_amdgcn_mfma_f32_16x16x32_bf16(pf, vb, o[hdf], 0, 0, 0);
      }
    }
    __builtin_amdgcn_s_setprio(0);
    if (jt < 15) {
      asm volatile("" ::: "memory");
      __builtin_amdgcn_s_barrier();
    }
  }
  const int b = bh >> 3, h = bh & 7;
#pragma unroll
  for (int hdf = 0; hdf < 4; hdf++)
#pragma unroll
    for (int r = 0; r < 4; r++) {
      float v = o[hdf][r] / l4s[r];
      int n = i0 + w * 16 + l4g * 4 + r;
      AO[((size_t)b * SEQ + n) * DMODEL + h * 64 + hdf * 16 + l15] = f2bf(v);
    }
}

// ---------------------------------------------------------------- LN ------
__global__ __launch_bounds__(256) void ln_kernel(
    const float* __restrict__ a, const float* __restrict__ res,
    const float* __restrict__ g, const float* __restrict__ be,
    float* __restrict__ outf, unsigned short* __restrict__ outb) {
  const int row = blockIdx.x, t = threadIdx.x;
  const float* pa = a + (size_t)row * DMODEL;
  const float* pb = res + (size_t)row * DMODEL;
  float v0 = pa[t] + pb[t];
  float v1 = pa[t + 256] + pb[t + 256];
  float s = v0 + v1, sq = v0 * v0 + v1 * v1;
#pragma unroll
  for (int off = 1; off < 64; off <<= 1) {
    s += __shfl_xor(s, off);
    sq += __shfl_xor(sq, off);
  }
  __shared__ float ls[4], lq[4];
  int w = t >> 6, lane = t & 63;
  if (lane == 0) { ls[w] = s; lq[w] = sq; }
  __syncthreads();
  s = ls[0] + ls[1] + ls[2] + ls[3];
  sq = lq[0] + lq[1] + lq[2] + lq[3];
  float mu = s * (1.f / DMODEL);
  float var = sq * (1.f / DMODEL) - mu * mu;
  float rs = rsqrtf(var + 1e-5f);
  float y0 = (v0 - mu) * rs * g[t] + be[t];
  float y1v = (v1 - mu) * rs * g[t + 256] + be[t + 256];
  outf[(size_t)row * DMODEL + t] = y0;
  outf[(size_t)row * DMODEL + t + 256] = y1v;
  if (outb) {
    outb[(size_t)row * DMODEL + t] = f2bf(y0);
    outb[(size_t)row * DMODEL + t + 256] = f2bf(y1v);
  }
}

// ---------------------------------------------------------------- launch --
extern "C" void kernel_launch(void* const* d_in, const int* in_sizes, int n_in,
                              void* d_out, int out_size, void* d_ws, size_t ws_size,
                              hipStream_t stream) {
  const float* x   = (const float*)d_in[0];
  const float* rel = (const float*)d_in[1];
  const float* Wq  = (const float*)d_in[2];
  const float* bq  = (const float*)d_in[3];
  const float* Wk  = (const float*)d_in[4];
  const float* bk  = (const float*)d_in[5];
  const float* Wv  = (const float*)d_in[6];
  const float* bv  = (const float*)d_in[7];
  const float* Wo  = (const float*)d_in[8];
  const float* bo  = (const float*)d_in[9];
  const float* R1  = (const float*)d_in[10];
  const float* rb1 = (const float*)d_in[11];
  const float* R2  = (const float*)d_in[12];
  const float* rb2 = (const float*)d_in[13];
  const float* g1  = (const float*)d_in[14];
  const float* b1  = (const float*)d_in[15];
  const float* g2  = (const float*)d_in[16];
  const float* b2  = (const float*)d_in[17];
  const float* F1  = (const float*)d_in[18];
  const float* fb1 = (const float*)d_in[19];
  const float* F2  = (const float*)d_in[20];
  const float* fb2 = (const float*)d_in[21];

  char* p = (char*)d_ws;
  auto alloc = [&](size_t bytes) {
    char* r = p;
    p += (bytes + 255) & ~(size_t)255;
    return r;
  };
  unsigned short* xb   = (unsigned short*)alloc((size_t)2048 * 512 * 2);
  unsigned short* qkvT = (unsigned short*)alloc((size_t)1536 * 512 * 2);
  float*          bqkv = (float*)alloc(1536 * 4);
  unsigned short* WoT  = (unsigned short*)alloc((size_t)512 * 512 * 2);
  unsigned short* F1T  = (unsigned short*)alloc((size_t)2048 * 512 * 2);
  unsigned short* F2T  = (unsigned short*)alloc((size_t)512 * 2048 * 2);
  unsigned short* Qhp  = (unsigned short*)alloc((size_t)BH * SEQ * HDIM * 2);
  unsigned short* Khp  = (unsigned short*)alloc((size_t)BH * SEQ * HDIM * 2);
  unsigned short* VTp  = (unsigned short*)alloc((size_t)BH * HDIM * SEQ * 2);
  unsigned short* rpep = (unsigned short*)alloc((size_t)BH * SEQ * SEQ * 2);   // 32MB
  unsigned short* attO = (unsigned short*)alloc((size_t)2048 * 512 * 2);
  float*          t1   = (float*)alloc((size_t)2048 * 512 * 4);
  float*          y1   = (float*)alloc((size_t)2048 * 512 * 4);
  unsigned short* y1b  = (unsigned short*)alloc((size_t)2048 * 512 * 2);
  float*          t2   = t1;                     // t1 dead after LN1
  unsigned short* hbuf = rpep;                   // rpe dead after attention

  prep_misc<<<1024, 256, 0, stream>>>(x, bq, bk, bv, xb, bqkv);
  prep_weights<<<3072, dim3(32, 8), 0, stream>>>(Wq, Wk, Wv, Wo, F1, F2,
                                                 qkvT, WoT, F1T, F2T);
  rpe_mfma<<<2048, 256, 0, stream>>>(rel, R1, rb1, R2, rb2, rpep);

  // QKV: 128x64 tiles -> 384 blocks
  gemm_bt<EPI_QKV, 128, 64, 4, 2><<<dim3(24, 16), 256, 0, stream>>>(
      xb, qkvT, bqkv, Qhp, Khp, VTp, 2048, 1536, 512);
  attn_kernel<<<256, 256, 0, stream>>>(Qhp, Khp, VTp, rpep, attO);

  // Wo: 64x64 tiles -> 256 blocks
  gemm_bt<EPI_F32, 64, 64, 2, 2><<<dim3(8, 32), 256, 0, stream>>>(
      attO, WoT, bo, t1, nullptr, nullptr, 2048, 512, 512);
  ln_kernel<<<2048, 256, 0, stream>>>(x, t1, g1, b1, y1, y1b);

  // FFN1: 128x64 tiles -> 512 blocks
  gemm_bt<EPI_GELU, 128, 64, 4, 2><<<dim3(32, 16), 256, 0, stream>>>(
      y1b, F1T, fb1, hbuf, nullptr, nullptr, 2048, 2048, 512);
  // FFN2: 64x64 tiles -> 256 blocks
  gemm_bt<EPI_F32, 64, 64, 2, 2><<<dim3(8, 32), 256, 0, stream>>>(
      hbuf, F2T, fb2, t2, nullptr, nullptr, 2048, 512, 2048);
  ln_kernel<<<2048, 256, 0, stream>>>(y1, t2, g2, b2, (float*)d_out, nullptr);
}